// Round 4
// baseline (669.271 us; speedup 1.0000x reference)
//
#include <hip/hip_runtime.h>
#include <hip/hip_bf16.h>
#include <cstdint>
#include <cstddef>

#define H_     64
#define P_     64
#define G_     8
#define N_     128
#define K_     4
#define CS_    256
#define HID_   2048
#define INTER_ 4096
#define CONVD_ 6144
#define PROJ_  10304
#define ZSTR_  10240   /* zb row stride: z + xBC only (dt has fp32 sidecar) */
#define B_     2
#define L_     2048
#define NC_    8
#define ML_    4096    /* B_*L_ */
#define EPS_   1e-5f

typedef unsigned short ushort_t;
typedef __attribute__((ext_vector_type(8))) short short8;
typedef __attribute__((ext_vector_type(4))) float f32x4;

__device__ inline float b2f(ushort_t v) {
  unsigned u = ((unsigned)v) << 16;
  float f;
  __builtin_memcpy(&f, &u, 4);
  return f;
}
__device__ inline ushort_t f2b(float f) {
  unsigned u;
  __builtin_memcpy(&u, &f, 4);
  u = u + 0x7FFFu + ((u >> 16) & 1u);   // round-to-nearest-even
  return (ushort_t)(u >> 16);
}
__device__ inline void ld_bf8(const ushort_t* p, float* f) {
  uint4 u = *(const uint4*)p;
  const ushort_t* s = (const ushort_t*)&u;
#pragma unroll
  for (int c = 0; c < 8; ++c) f[c] = b2f(s[c]);
}
__device__ inline void st_bf8(ushort_t* p, const float* f) {
  uint4 u;
  ushort_t* s = (ushort_t*)&u;
#pragma unroll
  for (int c = 0; c < 8; ++c) s[c] = f2b(f[c]);
  *(uint4*)p = u;
}

// ---------------------------------------------------------------------------
// fp32 -> bf16 cast kernel (hs + w_in)
// ---------------------------------------------------------------------------
__global__ __launch_bounds__(256) void cast1_k(const float* __restrict__ hs,
                                               const float* __restrict__ w_in,
                                               ushort_t* __restrict__ hsb,
                                               ushort_t* __restrict__ w_inb) {
  size_t e8 = ((size_t)blockIdx.x * 256 + threadIdx.x) * 8;
  const float* src;
  ushort_t* dst;
  const size_t HSN = (size_t)ML_ * HID_;          // 8388608
  if (e8 < HSN) { src = hs + e8; dst = hsb + e8; }
  else          { src = w_in + (e8 - HSN); dst = w_inb + (e8 - HSN); }
  float4 a = *(const float4*)src;
  float4 b = *(const float4*)(src + 4);
  float v[8] = {a.x, a.y, a.z, a.w, b.x, b.y, b.z, b.w};
  st_bf8(dst, v);
}

// ---------------------------------------------------------------------------
// global_load_lds helper (16B per lane, wave-uniform LDS base + lane*16)
// ---------------------------------------------------------------------------
typedef const __attribute__((address_space(1))) unsigned int gu32;
typedef __attribute__((address_space(3))) unsigned int lu32;
__device__ __forceinline__ void gl_lds16(const ushort_t* g, ushort_t* l) {
  __builtin_amdgcn_global_load_lds((gu32*)g, (lu32*)l, 16, 0, 0);
}

template<int N> __device__ __forceinline__ void wait_vmcnt() {
  if constexpr (N == 8)      asm volatile("s_waitcnt vmcnt(8)" ::: "memory");
  else if constexpr (N == 6) asm volatile("s_waitcnt vmcnt(6)" ::: "memory");
  else if constexpr (N == 4) asm volatile("s_waitcnt vmcnt(4)" ::: "memory");
  else if constexpr (N == 3) asm volatile("s_waitcnt vmcnt(3)" ::: "memory");
  else                       asm volatile("s_waitcnt vmcnt(0)" ::: "memory");
}
__device__ __forceinline__ void phase_barrier() {
  __builtin_amdgcn_s_barrier();
  asm volatile("" ::: "memory");
}

// ---------------------------------------------------------------------------
// MRx256-tile GEMM core (MR = 256 or 128). BK=32, 512 thr = 8 waves (2M x 4N),
// per-wave (MR/2)x64 output ((MR/32)x4 frags of 16x16x32 bf16 MFMA).
// Pipeline: 4-slot LDS ring, DEPTH-3 prefetch, counted vmcnt at K-tile
// boundary only (2*LPT steady, LPT, 0 drain).
// 8-PHASE PACING (m201 template): each K-tile = 2 phases of
//   {ds_read frags ; issue 1 stage ; s_barrier ; setprio(1) 16xMFMA
//    setprio(0) ; s_barrier}
// -> 4 barriers/kt = 16 per 128K, matching the verified template density.
// LDS swizzle: stored col-block = logical ^ ((row>>1)&3), applied on the
// pre-swizzled global source (linear gl_lds dest) AND on ds_read addresses.
// ---------------------------------------------------------------------------
template<int MR>
__device__ __forceinline__ void gemm_core(const ushort_t* __restrict__ Ag,
                                          const ushort_t* __restrict__ Bg,
                                          int lda, int ldb, int nkt,
                                          int bm, int bn, int brmax,
                                          ushort_t* __restrict__ As,
                                          ushort_t* __restrict__ Bs,
                                          f32x4 (&acc)[MR / 32][4]) {
  constexpr int MF = MR / 32;            // m-frags per wave (8 or 4)
  constexpr int ASLOT = MR * 32;         // elements per A ring slot
  constexpr int BSLOT = 256 * 32;
  constexpr int LPT = (MR == 256) ? 4 : 3;   // gl_lds issues per tile per wave
  const int t = threadIdx.x;
  const int w = t >> 6, l = t & 63;
  const int wm = w >> 2, wn = w & 3;
  const int ml = l & 15, q = l >> 4;
  const int swz = (ml >> 1) & 3;
  const int aoff = (wm * (MR / 2) + ml) * 32 + ((q ^ swz) << 3);
  const int boff = (wn * 64 + ml) * 32 + ((q ^ swz) << 3);
  // staging: lane l writes stored col-block (l&3) of row base+(l>>2);
  // source logical block = (l&3) ^ ((row>>1)&3) = (l&3) ^ ((l>>3)&3)
  const int permc = (((l & 3) ^ ((l >> 3) & 3)) << 3);
  const ushort_t* ag0 = Ag + (size_t)(bm + (MR / 8) * w + (l >> 2)) * lda + permc;
  const ushort_t* ag1 = ag0 + (size_t)16 * lda;        // MR==256 only
  int br0 = bn + 32 * w + (l >> 2);      if (br0 > brmax) br0 = brmax;
  int br1 = bn + 32 * w + 16 + (l >> 2); if (br1 > brmax) br1 = brmax;
  const ushort_t* bg0 = Bg + (size_t)br0 * ldb + permc;
  const ushort_t* bg1 = Bg + (size_t)br1 * ldb + permc;
  ushort_t* alw = As + ((MR == 256) ? (2 * w * 512) : (w * 512));
  ushort_t* blw = Bs + 2 * w * 512;

#define STAGE_A_(kt_)                                                        \
  { const int k_ = (kt_) << 5;                                               \
    ushort_t* sa_ = alw + ((kt_) & 3) * ASLOT;                               \
    gl_lds16(ag0 + k_, sa_);                                                 \
    if (MR == 256) gl_lds16(ag1 + k_, sa_ + 512); }
#define STAGE_B_(kt_)                                                        \
  { const int k_ = (kt_) << 5;                                               \
    ushort_t* sb_ = blw + ((kt_) & 3) * BSLOT;                               \
    gl_lds16(bg0 + k_, sb_);                                                 \
    gl_lds16(bg1 + k_, sb_ + 512); }

  // prologue: stage tiles 0,1,2 (nkt >= 3 always here)
  STAGE_A_(0); STAGE_B_(0);
  STAGE_A_(1); STAGE_B_(1);
  STAGE_A_(2); STAGE_B_(2);

#pragma unroll
  for (int i = 0; i < MF; ++i)
#pragma unroll
    for (int j = 0; j < 4; ++j) acc[i][j] = (f32x4){0.f, 0.f, 0.f, 0.f};

#pragma unroll 1
  for (int kt = 0; kt < nkt; ++kt) {
    const ushort_t* Asl = As + (kt & 3) * ASLOT;
    const ushort_t* Bsl = Bs + (kt & 3) * BSLOT;
    // tiles kt+1,kt+2 may be in flight (2*LPT loads); all older must be done
    if (kt + 2 < nkt)      wait_vmcnt<2 * LPT>();
    else if (kt + 1 < nkt) wait_vmcnt<LPT>();
    else                   wait_vmcnt<0>();
    phase_barrier();                       // slot kt published to all waves
    const bool st = (kt + 3) < nkt;
    // ---- phase 1: B frags + A m-half 0, stage next A ----
    short8 bfr[4], af[MF / 2];
#pragma unroll
    for (int nf = 0; nf < 4; ++nf)
      bfr[nf] = *(const short8*)(Bsl + boff + nf * 512);
#pragma unroll
    for (int mf = 0; mf < MF / 2; ++mf)
      af[mf] = *(const short8*)(Asl + aoff + mf * 512);
    if (st) STAGE_A_(kt + 3);
    phase_barrier();                       // all loads issued before MFMA burst
    __builtin_amdgcn_s_setprio(1);
#pragma unroll
    for (int mf = 0; mf < MF / 2; ++mf)
#pragma unroll
      for (int nf = 0; nf < 4; ++nf)
        acc[mf][nf] = __builtin_amdgcn_mfma_f32_16x16x32_bf16(af[mf], bfr[nf], acc[mf][nf], 0, 0, 0);
    __builtin_amdgcn_s_setprio(0);
    phase_barrier();                       // end phase 1
    // ---- phase 2: A m-half 1, stage next B ----
#pragma unroll
    for (int mf = 0; mf < MF / 2; ++mf)
      af[mf] = *(const short8*)(Asl + aoff + (mf + MF / 2) * 512);
    if (st) STAGE_B_(kt + 3);
    phase_barrier();
    __builtin_amdgcn_s_setprio(1);
#pragma unroll
    for (int mf = 0; mf < MF / 2; ++mf)
#pragma unroll
      for (int nf = 0; nf < 4; ++nf)
        acc[mf + MF / 2][nf] = __builtin_amdgcn_mfma_f32_16x16x32_bf16(af[mf], bfr[nf], acc[mf + MF / 2][nf], 0, 0, 0);
    __builtin_amdgcn_s_setprio(0);
  }
#undef STAGE_A_
#undef STAGE_B_
}

// GEMM1 main: M=4096, N=10496 (z cols 0..10239, dt cols 10240..10303 fp32
// TRANSPOSED to dtraw[64][4096]; cols 10304..10495 garbage/discarded; B rows
// clamped). grid 656 = 16m x 41n.
__global__ __launch_bounds__(512, 2) void gemm1_256(const ushort_t* __restrict__ hsb,
                                                    const ushort_t* __restrict__ w_inb,
                                                    ushort_t* __restrict__ zb,
                                                    float* __restrict__ dtraw) {
  __shared__ __align__(16) ushort_t As[4 * 8192];
  __shared__ __align__(16) ushort_t Bs[4 * 8192];
  int bid = blockIdx.x;
  int wg = (bid & 7) * 82 + (bid >> 3);          // bijective XCD swizzle (656%8==0)
  int tm = wg & 15, tn = wg >> 4;                // tm in [0,16), tn in [0,41)
  int bm = tm * 256, bn = tn * 256;
  f32x4 acc[8][4];
  gemm_core<256>(hsb, w_inb, HID_, HID_, HID_ / 32, bm, bn, PROJ_ - 1, As, Bs, acc);
  int t = threadIdx.x, w = t >> 6, l = t & 63;
  int wm = w >> 2, wn = w & 3, ml = l & 15, quad = l >> 4;
  int rb = bm + wm * 128 + quad * 4;
  int cb = bn + wn * 64 + ml;
  if (tn < 40) {
#pragma unroll
    for (int mf = 0; mf < 8; ++mf)
#pragma unroll
      for (int r = 0; r < 4; ++r) {
        size_t row = (size_t)(rb + mf * 16 + r) * ZSTR_;
#pragma unroll
        for (int nf = 0; nf < 4; ++nf)
          zb[row + cb + nf * 16] = f2b(acc[mf][nf][r]);
      }
  } else if (wn == 0) {   // dt columns, transposed store: dtraw[h][token]
#pragma unroll
    for (int mf = 0; mf < 8; ++mf)
#pragma unroll
      for (int r = 0; r < 4; ++r) {
        int tok = rb + mf * 16 + r;
#pragma unroll
        for (int nf = 0; nf < 4; ++nf)
          dtraw[(size_t)(ml + nf * 16) * ML_ + tok] = acc[mf][nf][r];
      }
  }
}

// GEMM2: out = Y @ out_proj_w^T. M=4096, N=2048, K=4096.
// 128x256 tiles -> grid 256 = 32m x 8n = exactly one full round of the GPU.
__global__ __launch_bounds__(512, 2) void gemm2_128(const ushort_t* __restrict__ Ab,
                                                    const ushort_t* __restrict__ Bb,
                                                    float* __restrict__ C) {
  __shared__ __align__(16) ushort_t As[4 * 4096];
  __shared__ __align__(16) ushort_t Bs[4 * 8192];
  int bid = blockIdx.x;
  int wg = (bid & 7) * 32 + (bid >> 3);          // 256%8==0
  int tm = wg & 31, tn = wg >> 5;
  int bm = tm * 128, bn = tn * 256;
  f32x4 acc[4][4];
  gemm_core<128>(Ab, Bb, CONVD_, INTER_, INTER_ / 32, bm, bn, HID_ - 1, As, Bs, acc);
  int t = threadIdx.x, w = t >> 6, l = t & 63;
  int wm = w >> 2, wn = w & 3, ml = l & 15, quad = l >> 4;
  int rb = bm + wm * 64 + quad * 4;
  int cb = bn + wn * 64 + ml;
#pragma unroll
  for (int mf = 0; mf < 4; ++mf)
#pragma unroll
    for (int r = 0; r < 4; ++r) {
      size_t row = (size_t)(rb + mf * 16 + r) * HID_;
#pragma unroll
      for (int nf = 0; nf < 4; ++nf)
        C[row + cb + nf * 16] = acc[mf][nf][r];
    }
}

// ---------------------------------------------------------------------------
// Fused launch: blocks [0,1536) causal depthwise conv (K=4)+SiLU;
// blocks [1536,2560) dt softplus+cumsum (reads TRANSPOSED dtraw -> coalesced).
// ---------------------------------------------------------------------------
#define CROWS_ 8
__global__ __launch_bounds__(256) void conv_dt_k(const ushort_t* __restrict__ zb,
                                                 const float* __restrict__ cw,
                                                 const float* __restrict__ cb,
                                                 ushort_t* __restrict__ xcb,
                                                 const float* __restrict__ dtraw,
                                                 const float* __restrict__ dt_bias,
                                                 const float* __restrict__ A_log,
                                                 float* __restrict__ dtp,
                                                 float* __restrict__ dacs,
                                                 float* __restrict__ cdec) {
  __shared__ float sm[256];
  int bid = blockIdx.x;
  if (bid < 1536) {
    // ---- conv + SiLU ----
    int grp = bid & 511;                 // ML_/CROWS_ = 512 row groups
    int seg = bid >> 9;                  // 3 segs x 2048 channels
    int u = threadIdx.x;                 // unit (8 channels) within seg
    int c8 = seg * 2048 + u * 8;
    int row0 = grp * CROWS_;             // groups never cross batch
    int l0 = row0 & (L_ - 1);

    float wv[K_][8], bias[8];
    {
      const float4* wp = (const float4*)(cw + (size_t)c8 * K_);
#pragma unroll
      for (int c = 0; c < 8; ++c) {
        float4 w4 = wp[c];
        wv[0][c] = w4.x; wv[1][c] = w4.y; wv[2][c] = w4.z; wv[3][c] = w4.w;
      }
      float4 b0 = *(const float4*)(cb + c8);
      float4 b1 = *(const float4*)(cb + c8 + 4);
      bias[0] = b0.x; bias[1] = b0.y; bias[2] = b0.z; bias[3] = b0.w;
      bias[4] = b1.x; bias[5] = b1.y; bias[6] = b1.z; bias[7] = b1.w;
    }
    const ushort_t* xin = zb + (size_t)row0 * ZSTR_ + INTER_ + c8;
    ushort_t* xout = xcb + (size_t)row0 * CONVD_ + c8;

    float win[4][8];
#pragma unroll
    for (int i = 0; i < 3; ++i) {
      if (l0 > 0) {
        ld_bf8(xin + (ptrdiff_t)(i - 3) * ZSTR_, win[i]);
      } else {
#pragma unroll
        for (int c = 0; c < 8; ++c) win[i][c] = 0.f;   // zero-pad (matches ref)
      }
    }
#pragma unroll
    for (int r = 0; r < CROWS_; ++r) {
      ld_bf8(xin + (size_t)r * ZSTR_, win[(r + 3) & 3]);
      float a[8];
#pragma unroll
      for (int c = 0; c < 8; ++c) {
        float v = bias[c];
        v = fmaf(wv[0][c], win[(r + 0) & 3][c], v);
        v = fmaf(wv[1][c], win[(r + 1) & 3][c], v);
        v = fmaf(wv[2][c], win[(r + 2) & 3][c], v);
        v = fmaf(wv[3][c], win[(r + 3) & 3][c], v);
        a[c] = v / (1.f + __expf(-v));
      }
      st_bf8(xout + (size_t)r * CONVD_, a);
    }
  } else {
    // ---- dt: softplus + per-chunk cumsum ----
    int bzh = bid - 1536;
    int h = bzh & 63, z = (bzh >> 6) & 7, b = bzh >> 9;
    int i = threadIdx.x;
    size_t row = (size_t)b * L_ + z * CS_ + i;
    float dv = dtraw[(size_t)h * ML_ + row] + dt_bias[h];
    float sp = (dv > 20.f) ? dv : log1pf(expf(dv));
    float v = sp * (-expf(A_log[h]));
    sm[i] = v;
    __syncthreads();
    for (int off = 1; off < 256; off <<= 1) {
      float add = (i >= off) ? sm[i - off] : 0.f;
      __syncthreads();
      sm[i] += add;
      __syncthreads();
    }
    float cs = sm[i];
    size_t ob = ((size_t)b * H_ + h) * L_ + z * CS_ + i;
    dtp[ob] = sp;
    dacs[ob] = cs;
    if (i == CS_ - 1) cdec[bzh] = expf(cs);
  }
}

// ---------------------------------------------------------------------------
// CB[i,j] = sum_n C[i,n]*B[j,n], lower-triangular 64x64 tiles. bf16 out.
// ---------------------------------------------------------------------------
__global__ __launch_bounds__(256) void cb_k(const ushort_t* __restrict__ xcb,
                                            ushort_t* __restrict__ CBo) {
  int jt = blockIdx.x & 3, it = blockIdx.x >> 2;
  if (jt > it) return;
  int bzg = blockIdx.y;
  int g = bzg & 7, z = (bzg >> 3) & 7, b = bzg >> 6;
  int t = threadIdx.x;
  int tx = t & 15, ty = t >> 4;
  __shared__ float CtT[64][68];
  __shared__ float BtT[64][68];
  size_t rowbase = (size_t)b * L_ + (size_t)z * CS_;
  float acc[4][4];
#pragma unroll
  for (int i = 0; i < 4; ++i)
#pragma unroll
    for (int j = 0; j < 4; ++j) acc[i][j] = 0.f;

  for (int half = 0; half < 2; ++half) {
    int nb = half * 64;
    __syncthreads();
#pragma unroll
    for (int u = 0; u < 2; ++u) {
      int idx = t + u * 256;
      int rr = idx >> 3, f = idx & 7;
      float cv[8], bv[8];
      ld_bf8(xcb + (rowbase + it * 64 + rr) * CONVD_ + INTER_ + G_ * N_ + g * N_ + nb + f * 8, cv);
      ld_bf8(xcb + (rowbase + jt * 64 + rr) * CONVD_ + INTER_ + g * N_ + nb + f * 8, bv);
#pragma unroll
      for (int c = 0; c < 8; ++c) { CtT[f * 8 + c][rr] = cv[c]; BtT[f * 8 + c][rr] = bv[c]; }
    }
    __syncthreads();
    for (int n = 0; n < 64; ++n) {
      float4 cv = *(const float4*)&CtT[n][ty * 4];
      float4 bv = *(const float4*)&BtT[n][tx * 4];
      float cc[4] = {cv.x, cv.y, cv.z, cv.w};
      float bb[4] = {bv.x, bv.y, bv.z, bv.w};
#pragma unroll
      for (int i = 0; i < 4; ++i)
#pragma unroll
        for (int j = 0; j < 4; ++j) acc[i][j] = fmaf(cc[i], bb[j], acc[i][j]);
    }
  }
  size_t cbase = ((size_t)((b * 8 + z) * 8 + g)) * (CS_ * CS_);
#pragma unroll
  for (int i = 0; i < 4; ++i) {
    int row = it * 64 + ty * 4 + i;
    ushort4 v;
    v.x = f2b(acc[i][0]); v.y = f2b(acc[i][1]); v.z = f2b(acc[i][2]); v.w = f2b(acc[i][3]);
    *(ushort4*)(CBo + cbase + (size_t)row * CS_ + jt * 64 + tx * 4) = v;
  }
}

// ---------------------------------------------------------------------------
// states (MFMA): S[p,n] = sum_j x[j,p]*w[j]*B[j,n] per (b,z,h).
// ---------------------------------------------------------------------------
__global__ __launch_bounds__(256) void states_mfma(const ushort_t* __restrict__ xcb,
                                                   const float* __restrict__ dacs,
                                                   const float* __restrict__ dtp,
                                                   float* __restrict__ st) {
  int bzh = blockIdx.x;
  int h = bzh & 63, z = (bzh >> 6) & 7, b = bzh >> 9;
  int g = h >> 3;
  int t = threadIdx.x;
  int wv = t >> 6, lane = t & 63;
  int ml = lane & 15, ko = (lane >> 4) * 8;
  __shared__ float ws[256];
  __shared__ __align__(16) ushort_t Xw[64 * 136];    // (w*x)^T [p][j_half]
  __shared__ __align__(16) ushort_t Bt[128 * 136];   // B^T [n][j_half]
  size_t base = ((size_t)b * H_ + h) * L_ + z * CS_;
  float dlast = dacs[base + CS_ - 1];
  ws[t] = __expf(dlast - dacs[base + t]) * dtp[base + t];
  size_t rowbase = (size_t)b * L_ + z * CS_;
  f32x4 acc[4][2];
#pragma unroll
  for (int i = 0; i < 4; ++i) {
    acc[i][0] = (f32x4){0.f, 0.f, 0.f, 0.f};
    acc[i][1] = (f32x4){0.f, 0.f, 0.f, 0.f};
  }
  for (int half = 0; half < 2; ++half) {
    int j0 = half * 128;
    __syncthreads();
    {   // stage Xw: x[j][p]*w[j] -> Xw[p][jl]
      int jl = t >> 1, pseg = (t & 1) * 32;
      const ushort_t* xr = xcb + (rowbase + j0 + jl) * CONVD_ + h * P_ + pseg;
      float wj = ws[j0 + jl];
#pragma unroll
      for (int q = 0; q < 4; ++q) {
        float v[8];
        ld_bf8(xr + q * 8, v);
#pragma unroll
        for (int c = 0; c < 8; ++c) Xw[(pseg + q * 8 + c) * 136 + jl] = f2b(v[c] * wj);
      }
    }
    {   // stage Bt: B[j][n] -> Bt[n][jl]
      int jl = t >> 1, nseg = (t & 1) * 64;
      const ushort_t* br = xcb + (rowbase + j0 + jl) * CONVD_ + INTER_ + g * N_ + nseg;
#pragma unroll
      for (int q = 0; q < 8; ++q) {
        uint4 raw = *(const uint4*)(br + q * 8);
        const ushort_t* s = (const ushort_t*)&raw;
#pragma unroll
        for (int c = 0; c < 8; ++c) Bt[(nseg + q * 8 + c) * 136 + jl] = s[c];
      }
    }
    __syncthreads();
#pragma unroll
    for (int k0 = 0; k0 < 128; k0 += 32) {
      short8 af[4], bf2[2];
#pragma unroll
      for (int mf = 0; mf < 4; ++mf)
        af[mf] = *(const short8*)(Xw + (mf * 16 + ml) * 136 + k0 + ko);
#pragma unroll
      for (int nf = 0; nf < 2; ++nf)
        bf2[nf] = *(const short8*)(Bt + (wv * 32 + nf * 16 + ml) * 136 + k0 + ko);
#pragma unroll
      for (int mf = 0; mf < 4; ++mf)
#pragma unroll
        for (int nf = 0; nf < 2; ++nf)
          acc[mf][nf] = __builtin_amdgcn_mfma_f32_16x16x32_bf16(af[mf], bf2[nf], acc[mf][nf], 0, 0, 0);
    }
  }
  float* outp = st + ((size_t)((b * 8 + z) * H_ + h)) * (P_ * N_);
  int quad = lane >> 4;
#pragma unroll
  for (int mf = 0; mf < 4; ++mf)
#pragma unroll
    for (int nf = 0; nf < 2; ++nf) {
      int n = wv * 32 + nf * 16 + ml;
#pragma unroll
      for (int r = 0; r < 4; ++r) {
        int p = mf * 16 + quad * 4 + r;
        outp[(size_t)p * N_ + n] = acc[mf][nf][r];
      }
    }
}

// ---------------------------------------------------------------------------
// Inter-chunk exclusive scan over nc=8 chunks, IN PLACE on st.
// ---------------------------------------------------------------------------
__global__ __launch_bounds__(256) void scan_k(float* __restrict__ st,
                                              const float* __restrict__ cdec) {
  size_t idx = (size_t)blockIdx.x * 256 + threadIdx.x;
  int b = (int)(idx >> 19);            // 524288 = H_*P_*N_
  size_t rem = idx & 524287;
  int h = (int)(rem >> 13);            // 8192 = P_*N_
  float S = 0.f;
#pragma unroll
  for (int z = 0; z < NC_; ++z) {
    size_t off = (size_t)(b * 8 + z) * 524288 + rem;
    float old = st[off];
    st[off] = S;
    S = cdec[(b * 8 + z) * H_ + h] * S + old;
  }
}

// ---------------------------------------------------------------------------
// y (MFMA): Y^T[p][i] = exp(dA_i)*(prev@C^T) + M@x^T, + D*x, per (b,z,h).
// ---------------------------------------------------------------------------
__global__ __launch_bounds__(256) void y_mfma(const ushort_t* xcb,
                                              const ushort_t* __restrict__ CB,
                                              const float* __restrict__ pv,
                                              const float* __restrict__ dacs,
                                              const float* __restrict__ dtp,
                                              const float* __restrict__ Dw,
                                              ushort_t* Yx) {
  int bzh = blockIdx.x;
  int h = bzh & 63, z = (bzh >> 6) & 7, b = bzh >> 9;
  int g = h >> 3;
  int t = threadIdx.x;
  int wv = t >> 6, lane = t & 63;
  int ml = lane & 15, quad = lane >> 4, ko = quad * 8;
  __shared__ __align__(16) ushort_t Ms[256 * 40];    // Phase B M; Phase A Cs[256*32]
  __shared__ __align__(16) ushort_t XsYs[18432];     // Xs [64][264]; epilogue Ys [256][72]
  __shared__ __align__(16) ushort_t Ps[64 * 136];    // prev bf16 [p][n]
  __shared__ float dAs[256], dts[256];

  size_t rowbase = (size_t)b * L_ + z * CS_;
  {
    size_t base = ((size_t)b * H_ + h) * L_ + z * CS_;
    dAs[t] = dacs[base + t];
    dts[t] = dtp[base + t];
  }
  {   // stage prev fp32 -> bf16 Ps[p][n] (pad 136)
    int p = t >> 2, c0 = (t & 3) * 32;
    const float* pr = pv + ((size_t)((b * 8 + z) * H_ + h)) * (P_ * N_) + (size_t)p * N_ + c0;
    ushort_t* dst = Ps + p * 136 + c0;
#pragma unroll
    for (int u = 0; u < 4; ++u) {
      float4 a = *(const float4*)(pr + u * 8);
      float4 bq = *(const float4*)(pr + u * 8 + 4);
      float v[8] = {a.x, a.y, a.z, a.w, bq.x, bq.y, bq.z, bq.w};
      st_bf8(dst + u * 8, v);
    }
  }
  {   // stage Xs = x^T: read x[i=t][0..63], scatter to Xs[p][t]
    const ushort_t* xr = xcb + (rowbase + t) * CONVD_ + h * P_;
    ushort_t* Xs = XsYs;
#pragma unroll
    for (int q = 0; q < 8; ++q) {
      uint4 raw = *(const uint4*)(xr + q * 8);
      const ushort_t* s = (const ushort_t*)&raw;
#pragma unroll
      for (int c = 0; c < 8; ++c) Xs[(q * 8 + c) * 264 + t] = s[c];
    }
  }

  f32x4 acc[4][4];
#pragma unroll
  for (int i = 0; i < 4; ++i)
#pragma unroll
    for (int j = 0; j < 4; ++j) acc[i][j] = (f32x4){0.f, 0.f, 0.f, 0.f};

  // ---- Phase A: Y_off^T[p][i] = sum_n prev[p][n] * C[i][n]
  int cOff = INTER_ + G_ * N_ + g * N_;
#pragma unroll
  for (int k0 = 0; k0 < 128; k0 += 32) {
    __syncthreads();
#pragma unroll
    for (int u = 0; u < 4; ++u) {   // stage Cs tile [256][32] via global_load_lds
      int sid = u * 256 + t;
      int row = sid >> 2, kc = (sid & 3) * 8;
      gl_lds16(xcb + (rowbase + row) * CONVD_ + cOff + k0 + kc,
               Ms + (size_t)(u * 256 + wv * 64) * 8);
    }
    __syncthreads();
    short8 af[4], bf[4];
#pragma unroll
    for (int mf = 0; mf < 4; ++mf)
      af[mf] = *(const short8*)(Ps + (mf * 16 + ml) * 136 + k0 + ko);
#pragma unroll
    for (int nf = 0; nf < 4; ++nf)
      bf[nf] = *(const short8*)(Ms + (wv * 64 + nf * 16 + ml) * 32 + ko);
#pragma unroll
    for (int mf = 0; mf < 4; ++mf)
#pragma unroll
      for (int nf = 0; nf < 4; ++nf)
        acc[mf][nf] = __builtin_amdgcn_mfma_f32_16x16x32_bf16(af[mf], bf[nf], acc[mf][nf], 0, 0, 0);
  }
  // scale by exp(dA_i), i = column index
#pragma unroll
  for (int nf = 0; nf < 4; ++nf) {
    float e = __expf(dAs[wv * 64 + nf * 16 + ml]);
#pragma unroll
    for (int mf = 0; mf < 4; ++mf) {
      acc[mf][nf][0] *= e; acc[mf][nf][1] *= e;
      acc[mf][nf][2] *= e; acc[mf][nf][3] *= e;
    }
  }

  // ---- Phase B: Y_diag^T[p][i] = sum_j M[i][j] * x[j][p]
  float dAi_t = dAs[t];
  size_t cbase = ((size_t)((b * 8 + z) * 8 + g)) * (CS_ * CS_) + (size_t)t * CS_;
  const ushort_t* Xs = XsYs;
  for (int j0 = 0; j0 < 256; j0 += 32) {
    __syncthreads();
    {   // build M row i=t, cols j0..j0+31 into Ms[t][0..31] (stride 40)
      const ushort_t* cbr = CB + cbase + j0;
      ushort_t* mrow = Ms + t * 40;
#pragma unroll
      for (int q = 0; q < 4; ++q) {
        float cv[8], o[8];
        ld_bf8(cbr + q * 8, cv);
#pragma unroll
        for (int c = 0; c < 8; ++c) {
          int j = j0 + q * 8 + c;
          float m = cv[c] * __expf(dAi_t - dAs[j]) * dts[j];
          o[c] = (j <= t) ? m : 0.f;
        }
        st_bf8(mrow + q * 8, o);
      }
    }
    __syncthreads();
    short8 af[4], bf[4];
#pragma unroll
    for (int mf = 0; mf < 4; ++mf)
      af[mf] = *(const short8*)(Xs + (mf * 16 + ml) * 264 + j0 + ko);
#pragma unroll
    for (int nf = 0; nf < 4; ++nf)
      bf[nf] = *(const short8*)(Ms + (wv * 64 + nf * 16 + ml) * 40 + ko);
#pragma unroll
    for (int mf = 0; mf < 4; ++mf)
#pragma unroll
      for (int nf = 0; nf < 4; ++nf)
        acc[mf][nf] = __builtin_amdgcn_mfma_f32_16x16x32_bf16(af[mf], bf[nf], acc[mf][nf], 0, 0, 0);
  }

  // ---- Epilogue: transpose acc through LDS (Ys over Xs), +D*x, store
  __syncthreads();
  ushort_t* Ys = XsYs;   // [256][72]
#pragma unroll
  for (int mf = 0; mf < 4; ++mf)
#pragma unroll
    for (int nf = 0; nf < 4; ++nf) {
      int iw = wv * 64 + nf * 16 + ml;
      int pb = mf * 16 + quad * 4;
      uint2 pk;
      ushort_t* s = (ushort_t*)&pk;
      s[0] = f2b(acc[mf][nf][0]); s[1] = f2b(acc[mf][nf][1]);
      s[2] = f2b(acc[mf][nf][2]); s[3] = f2b(acc[mf][nf][3]);
      *(uint2*)(Ys + iw * 72 + pb) = pk;
    }
  __syncthreads();
  {
    float Dh = Dw[h];
    const ushort_t* xr = xcb + (rowbase + t) * CONVD_ + h * P_;
    ushort_t* yr = Yx + (rowbase + t) * CONVD_ + h * P_;
#pragma unroll
    for (int q = 0; q < 8; ++q) {
      float xv[8], yv[8], o[8];
      ld_bf8(xr + q * 8, xv);
      ld_bf8(Ys + t * 72 + q * 8, yv);
#pragma unroll
      for (int c = 0; c < 8; ++c) o[c] = yv[c] + Dh * xv[c];
      st_bf8(yr + q * 8, o);
    }
  }
}

// ---------------------------------------------------------------------------
// Fused launch: blocks [0,4096) RMSNorm + silu(z) gate (in-place on xcb
// x-slice); blocks [4096,8192) cast w_out fp32 -> bf16 (independent work).
// ---------------------------------------------------------------------------
__global__ __launch_bounds__(256) void rms_cast2_k(ushort_t* __restrict__ Y,
                                                   const ushort_t* __restrict__ zb,
                                                   const float* __restrict__ nw,
                                                   const float* __restrict__ w_out,
                                                   ushort_t* __restrict__ w_outb) {
  __shared__ float red[4];
  int bid = blockIdx.x;
  int t = threadIdx.x;
  if (bid >= ML_) {
    size_t e8 = ((size_t)(bid - ML_) * 256 + t) * 8;
    float4 a = *(const float4*)(w_out + e8);
    float4 b = *(const float4*)(w_out + e8 + 4);
    float v[8] = {a.x, a.y, a.z, a.w, b.x, b.y, b.z, b.w};
    st_bf8(w_outb + e8, v);
    return;
  }
  int row = bid;
  ushort_t* y = Y + (size_t)row * CONVD_;
  const ushort_t* zp = zb + (size_t)row * ZSTR_;
  float v[2][8];
  float s = 0.f;
#pragma unroll
  for (int u = 0; u < 2; ++u) {
    ld_bf8(y + u * 2048 + t * 8, v[u]);
#pragma unroll
    for (int c = 0; c < 8; ++c) s += v[u][c] * v[u][c];
  }
#pragma unroll
  for (int off = 32; off > 0; off >>= 1) s += __shfl_down(s, off);
  if ((t & 63) == 0) red[t >> 6] = s;
  __syncthreads();
  float tot = red[0] + red[1] + red[2] + red[3];
  float rstd = rsqrtf(tot * (1.f / INTER_) + EPS_);
#pragma unroll
  for (int u = 0; u < 2; ++u) {
    int c0 = u * 2048 + t * 8;
    float zv[8], o[8];
    ld_bf8(zp + c0, zv);
    float4 w0 = *(const float4*)(nw + c0);
    float4 w1 = *(const float4*)(nw + c0 + 4);
    float wv[8] = {w0.x, w0.y, w0.z, w0.w, w1.x, w1.y, w1.z, w1.w};
#pragma unroll
    for (int c = 0; c < 8; ++c)
      o[c] = wv[c] * v[u][c] * rstd * (zv[c] / (1.f + __expf(-zv[c])));
    st_bf8(y + c0, o);
  }
}

// ---------------------------------------------------------------------------
extern "C" void kernel_launch(void* const* d_in, const int* in_sizes, int n_in,
                              void* d_out, int out_size, void* d_ws, size_t ws_size,
                              hipStream_t stream) {
  const float* hs    = (const float*)d_in[0];
  const float* w_in  = (const float*)d_in[1];
  const float* cw    = (const float*)d_in[2];
  const float* cb    = (const float*)d_in[3];
  const float* dtb   = (const float*)d_in[4];
  const float* alog  = (const float*)d_in[5];
  const float* Dw    = (const float*)d_in[6];
  const float* nw    = (const float*)d_in[7];
  const float* w_out = (const float*)d_in[8];
  float* out = (float*)d_out;

  // Workspace layout (~187.3 MiB), regions R1/R2 time-aliased:
  //   R1: hsb [cast1,gemm1] -> cbuf [cb_k..y] -> w_outb [rms_cast2,gemm2]
  //   R2: w_inb [cast1,gemm1] -> st [states..y]
  char* base = (char*)d_ws;
  ushort_t* zb    = (ushort_t*)(base);                         //  83,886,080 B
  ushort_t* xcb   = (ushort_t*)(base + 83886080);              //  50,331,648 B
  float*    dtraw = (float*)(base + 134217728);                //   1,048,576 B
  float*    dtp   = (float*)(base + 135266304);                //   1,048,576 B
  float*    dacs  = (float*)(base + 136314880);                //   1,048,576 B
  float*    cdec  = (float*)(base + 137363456);                //       4,096 B
  char*     R1    = base + 137367552;                          //  16,777,216 B
  char*     R2    = base + 154144768;                          //  42,205,184 B
  ushort_t* hsb    = (ushort_t*)R1;
  ushort_t* cbuf   = (ushort_t*)R1;
  ushort_t* w_outb = (ushort_t*)R1;
  ushort_t* w_inb  = (ushort_t*)R2;
  float*    st     = (float*)R2;

  cast1_k<<<14400, 256, 0, stream>>>(hs, w_in, hsb, w_inb);
  gemm1_256<<<656, 512, 0, stream>>>(hsb, w_inb, zb, dtraw);
  conv_dt_k<<<2560, 256, 0, stream>>>(zb, cw, cb, xcb, dtraw, dtb, alog, dtp, dacs, cdec);
  cb_k<<<dim3(16, B_ * NC_ * G_), 256, 0, stream>>>(xcb, cbuf);
  states_mfma<<<B_ * NC_ * H_, 256, 0, stream>>>(xcb, dacs, dtp, st);
  scan_k<<<(B_ * H_ * P_ * N_) / 256, 256, 0, stream>>>(st, cdec);
  y_mfma<<<B_ * NC_ * H_, 256, 0, stream>>>(xcb, cbuf, st, dacs, dtp, Dw, xcb);
  rms_cast2_k<<<8192, 256, 0, stream>>>(xcb, zb, nw, w_out, w_outb);
  gemm2_128<<<256, 512, 0, stream>>>(xcb, w_outb, out);
}

// Round 5
// 629.595 us; speedup vs baseline: 1.0630x; 1.0630x over previous
//
#include <hip/hip_runtime.h>
#include <hip/hip_bf16.h>
#include <cstdint>
#include <cstddef>

#define H_     64
#define P_     64
#define G_     8
#define N_     128
#define K_     4
#define CS_    256
#define HID_   2048
#define INTER_ 4096
#define CONVD_ 6144
#define PROJ_  10304
#define ZSTR_  10240   /* zb row stride: z + xBC only (dt has fp32 sidecar) */
#define B_     2
#define L_     2048
#define NC_    8
#define ML_    4096    /* B_*L_ */
#define EPS_   1e-5f

typedef unsigned short ushort_t;
typedef __attribute__((ext_vector_type(8))) short short8;
typedef __attribute__((ext_vector_type(4))) float f32x4;

__device__ inline float b2f(ushort_t v) {
  unsigned u = ((unsigned)v) << 16;
  float f;
  __builtin_memcpy(&f, &u, 4);
  return f;
}
__device__ inline ushort_t f2b(float f) {
  unsigned u;
  __builtin_memcpy(&u, &f, 4);
  u = u + 0x7FFFu + ((u >> 16) & 1u);   // round-to-nearest-even
  return (ushort_t)(u >> 16);
}
__device__ inline void ld_bf8(const ushort_t* p, float* f) {
  uint4 u = *(const uint4*)p;
  const ushort_t* s = (const ushort_t*)&u;
#pragma unroll
  for (int c = 0; c < 8; ++c) f[c] = b2f(s[c]);
}
__device__ inline void st_bf8(ushort_t* p, const float* f) {
  uint4 u;
  ushort_t* s = (ushort_t*)&u;
#pragma unroll
  for (int c = 0; c < 8; ++c) s[c] = f2b(f[c]);
  *(uint4*)p = u;
}

// ---------------------------------------------------------------------------
// fp32 -> bf16 cast kernel (hs + w_in)
// ---------------------------------------------------------------------------
__global__ __launch_bounds__(256) void cast1_k(const float* __restrict__ hs,
                                               const float* __restrict__ w_in,
                                               ushort_t* __restrict__ hsb,
                                               ushort_t* __restrict__ w_inb) {
  size_t e8 = ((size_t)blockIdx.x * 256 + threadIdx.x) * 8;
  const float* src;
  ushort_t* dst;
  const size_t HSN = (size_t)ML_ * HID_;          // 8388608
  if (e8 < HSN) { src = hs + e8; dst = hsb + e8; }
  else          { src = w_in + (e8 - HSN); dst = w_inb + (e8 - HSN); }
  float4 a = *(const float4*)src;
  float4 b = *(const float4*)(src + 4);
  float v[8] = {a.x, a.y, a.z, a.w, b.x, b.y, b.z, b.w};
  st_bf8(dst, v);
}

// ---------------------------------------------------------------------------
// global_load_lds helper (16B per lane, wave-uniform LDS base + lane*16)
// ---------------------------------------------------------------------------
typedef const __attribute__((address_space(1))) unsigned int gu32;
typedef __attribute__((address_space(3))) unsigned int lu32;
__device__ __forceinline__ void gl_lds16(const ushort_t* g, ushort_t* l) {
  __builtin_amdgcn_global_load_lds((gu32*)g, (lu32*)l, 16, 0, 0);
}

template<int N> __device__ __forceinline__ void wait_vmcnt() {
  if constexpr (N == 8)      asm volatile("s_waitcnt vmcnt(8)" ::: "memory");
  else if constexpr (N == 6) asm volatile("s_waitcnt vmcnt(6)" ::: "memory");
  else if constexpr (N == 4) asm volatile("s_waitcnt vmcnt(4)" ::: "memory");
  else if constexpr (N == 3) asm volatile("s_waitcnt vmcnt(3)" ::: "memory");
  else                       asm volatile("s_waitcnt vmcnt(0)" ::: "memory");
}

// ---------------------------------------------------------------------------
// MRx256-tile GEMM core (MR = 256 or 128). BK=32, 512 thr = 8 waves (2M x 4N),
// per-wave (MR/2)x64 output ((MR/32)x4 frags of 16x16x32 bf16 MFMA).
// Pipeline: 4-slot LDS ring, DEPTH-3 prefetch (stage tile t+3 while computing
// t). ONE raw s_barrier + one counted vmcnt per K-tile (round-3 proven
// schedule; round-4's 4-barrier phase pacing REGRESSED -20 us, reverted).
// LDS swizzle: stored col-block = logical ^ ((row>>1)&3), applied on the
// pre-swizzled global source (linear gl_lds dest) AND on ds_read addresses.
// ---------------------------------------------------------------------------
template<int MR>
__device__ __forceinline__ void gemm_core(const ushort_t* __restrict__ Ag,
                                          const ushort_t* __restrict__ Bg,
                                          int lda, int ldb, int nkt,
                                          int bm, int bn, int brmax,
                                          ushort_t* __restrict__ As,
                                          ushort_t* __restrict__ Bs,
                                          f32x4 (&acc)[MR / 32][4]) {
  constexpr int MF = MR / 32;            // m-frags per wave (8 or 4)
  constexpr int ASLOT = MR * 32;         // elements per A ring slot
  constexpr int BSLOT = 256 * 32;
  constexpr int LPT = (MR == 256) ? 4 : 3;   // gl_lds issues per tile per wave
  const int t = threadIdx.x;
  const int w = t >> 6, l = t & 63;
  const int wm = w >> 2, wn = w & 3;
  const int ml = l & 15, q = l >> 4;
  const int swz = (ml >> 1) & 3;
  const int aoff = (wm * (MR / 2) + ml) * 32 + ((q ^ swz) << 3);
  const int boff = (wn * 64 + ml) * 32 + ((q ^ swz) << 3);
  // staging: lane l writes stored col-block (l&3) of row base+(l>>2);
  // source logical block = (l&3) ^ ((row>>1)&3) = (l&3) ^ ((l>>3)&3)
  const int permc = (((l & 3) ^ ((l >> 3) & 3)) << 3);
  const ushort_t* ag0 = Ag + (size_t)(bm + (MR / 8) * w + (l >> 2)) * lda + permc;
  const ushort_t* ag1 = ag0 + (size_t)16 * lda;        // MR==256 only
  int br0 = bn + 32 * w + (l >> 2);      if (br0 > brmax) br0 = brmax;
  int br1 = bn + 32 * w + 16 + (l >> 2); if (br1 > brmax) br1 = brmax;
  const ushort_t* bg0 = Bg + (size_t)br0 * ldb + permc;
  const ushort_t* bg1 = Bg + (size_t)br1 * ldb + permc;
  ushort_t* alw = As + ((MR == 256) ? (2 * w * 512) : (w * 512));
  ushort_t* blw = Bs + 2 * w * 512;

#define STAGE_A_(kt_)                                                        \
  { const int k_ = (kt_) << 5;                                               \
    ushort_t* sa_ = alw + ((kt_) & 3) * ASLOT;                               \
    gl_lds16(ag0 + k_, sa_);                                                 \
    if (MR == 256) gl_lds16(ag1 + k_, sa_ + 512); }
#define STAGE_B_(kt_)                                                        \
  { const int k_ = (kt_) << 5;                                               \
    ushort_t* sb_ = blw + ((kt_) & 3) * BSLOT;                               \
    gl_lds16(bg0 + k_, sb_);                                                 \
    gl_lds16(bg1 + k_, sb_ + 512); }

  // prologue: stage tiles 0,1,2 (nkt >= 3 always here)
  STAGE_A_(0); STAGE_B_(0);
  STAGE_A_(1); STAGE_B_(1);
  STAGE_A_(2); STAGE_B_(2);

#pragma unroll
  for (int i = 0; i < MF; ++i)
#pragma unroll
    for (int j = 0; j < 4; ++j) acc[i][j] = (f32x4){0.f, 0.f, 0.f, 0.f};

#pragma unroll 1
  for (int kt = 0; kt < nkt; ++kt) {
    const ushort_t* Asl = As + (kt & 3) * ASLOT;
    const ushort_t* Bsl = Bs + (kt & 3) * BSLOT;
    // tiles kt+1,kt+2 may be in flight (2*LPT loads); all older must be done
    if (kt + 2 < nkt)      wait_vmcnt<2 * LPT>();
    else if (kt + 1 < nkt) wait_vmcnt<LPT>();
    else                   wait_vmcnt<0>();
    __builtin_amdgcn_s_barrier();
    asm volatile("" ::: "memory");
    const bool st = (kt + 3) < nkt;
    short8 bfr[4], af[MF / 2];
#pragma unroll
    for (int nf = 0; nf < 4; ++nf)
      bfr[nf] = *(const short8*)(Bsl + boff + nf * 512);
#pragma unroll
    for (int mf = 0; mf < MF / 2; ++mf)
      af[mf] = *(const short8*)(Asl + aoff + mf * 512);
    if (st) STAGE_A_(kt + 3);
    __builtin_amdgcn_s_setprio(1);
#pragma unroll
    for (int mf = 0; mf < MF / 2; ++mf)
#pragma unroll
      for (int nf = 0; nf < 4; ++nf)
        acc[mf][nf] = __builtin_amdgcn_mfma_f32_16x16x32_bf16(af[mf], bfr[nf], acc[mf][nf], 0, 0, 0);
    __builtin_amdgcn_s_setprio(0);
#pragma unroll
    for (int mf = 0; mf < MF / 2; ++mf)
      af[mf] = *(const short8*)(Asl + aoff + (mf + MF / 2) * 512);
    if (st) STAGE_B_(kt + 3);
    __builtin_amdgcn_s_setprio(1);
#pragma unroll
    for (int mf = 0; mf < MF / 2; ++mf)
#pragma unroll
      for (int nf = 0; nf < 4; ++nf)
        acc[mf + MF / 2][nf] = __builtin_amdgcn_mfma_f32_16x16x32_bf16(af[mf], bfr[nf], acc[mf + MF / 2][nf], 0, 0, 0);
    __builtin_amdgcn_s_setprio(0);
  }
#undef STAGE_A_
#undef STAGE_B_
}

// GEMM1 main: M=4096, N=10496 (z cols 0..10239, dt cols 10240..10303 fp32
// TRANSPOSED to dtraw[64][4096]; cols 10304..10495 garbage/discarded; B rows
// clamped). grid 656 = 16m x 41n.
__global__ __launch_bounds__(512, 2) void gemm1_256(const ushort_t* __restrict__ hsb,
                                                    const ushort_t* __restrict__ w_inb,
                                                    ushort_t* __restrict__ zb,
                                                    float* __restrict__ dtraw) {
  __shared__ __align__(16) ushort_t As[4 * 8192];
  __shared__ __align__(16) ushort_t Bs[4 * 8192];
  int bid = blockIdx.x;
  int wg = (bid & 7) * 82 + (bid >> 3);          // bijective XCD swizzle (656%8==0)
  int tm = wg & 15, tn = wg >> 4;                // tm in [0,16), tn in [0,41)
  int bm = tm * 256, bn = tn * 256;
  f32x4 acc[8][4];
  gemm_core<256>(hsb, w_inb, HID_, HID_, HID_ / 32, bm, bn, PROJ_ - 1, As, Bs, acc);
  int t = threadIdx.x, w = t >> 6, l = t & 63;
  int wm = w >> 2, wn = w & 3, ml = l & 15, quad = l >> 4;
  int rb = bm + wm * 128 + quad * 4;
  int cb = bn + wn * 64 + ml;
  if (tn < 40) {
#pragma unroll
    for (int mf = 0; mf < 8; ++mf)
#pragma unroll
      for (int r = 0; r < 4; ++r) {
        size_t row = (size_t)(rb + mf * 16 + r) * ZSTR_;
#pragma unroll
        for (int nf = 0; nf < 4; ++nf)
          zb[row + cb + nf * 16] = f2b(acc[mf][nf][r]);
      }
  } else if (wn == 0) {   // dt columns, transposed store: dtraw[h][token]
#pragma unroll
    for (int mf = 0; mf < 8; ++mf)
#pragma unroll
      for (int r = 0; r < 4; ++r) {
        int tok = rb + mf * 16 + r;
#pragma unroll
        for (int nf = 0; nf < 4; ++nf)
          dtraw[(size_t)(ml + nf * 16) * ML_ + tok] = acc[mf][nf][r];
      }
  }
}

// GEMM2: out = Y @ out_proj_w^T. M=4096, N=2048, K=4096.
// 128x256 tiles -> grid 256 = 32m x 8n = exactly one full round of the GPU.
__global__ __launch_bounds__(512, 2) void gemm2_128(const ushort_t* __restrict__ Ab,
                                                    const ushort_t* __restrict__ Bb,
                                                    float* __restrict__ C) {
  __shared__ __align__(16) ushort_t As[4 * 4096];
  __shared__ __align__(16) ushort_t Bs[4 * 8192];
  int bid = blockIdx.x;
  int wg = (bid & 7) * 32 + (bid >> 3);          // 256%8==0
  int tm = wg & 31, tn = wg >> 5;
  int bm = tm * 128, bn = tn * 256;
  f32x4 acc[4][4];
  gemm_core<128>(Ab, Bb, CONVD_, INTER_, INTER_ / 32, bm, bn, HID_ - 1, As, Bs, acc);
  int t = threadIdx.x, w = t >> 6, l = t & 63;
  int wm = w >> 2, wn = w & 3, ml = l & 15, quad = l >> 4;
  int rb = bm + wm * 64 + quad * 4;
  int cb = bn + wn * 64 + ml;
#pragma unroll
  for (int mf = 0; mf < 4; ++mf)
#pragma unroll
    for (int r = 0; r < 4; ++r) {
      size_t row = (size_t)(rb + mf * 16 + r) * HID_;
#pragma unroll
      for (int nf = 0; nf < 4; ++nf)
        C[row + cb + nf * 16] = acc[mf][nf][r];
    }
}

// ---------------------------------------------------------------------------
// Fused launch: blocks [0,1536) causal depthwise conv (K=4)+SiLU;
// blocks [1536,2560) dt softplus+cumsum (reads TRANSPOSED dtraw -> coalesced).
// ---------------------------------------------------------------------------
#define CROWS_ 8
__global__ __launch_bounds__(256) void conv_dt_k(const ushort_t* __restrict__ zb,
                                                 const float* __restrict__ cw,
                                                 const float* __restrict__ cb,
                                                 ushort_t* __restrict__ xcb,
                                                 const float* __restrict__ dtraw,
                                                 const float* __restrict__ dt_bias,
                                                 const float* __restrict__ A_log,
                                                 float* __restrict__ dtp,
                                                 float* __restrict__ dacs,
                                                 float* __restrict__ cdec) {
  __shared__ float sm[256];
  int bid = blockIdx.x;
  if (bid < 1536) {
    // ---- conv + SiLU ----
    int grp = bid & 511;                 // ML_/CROWS_ = 512 row groups
    int seg = bid >> 9;                  // 3 segs x 2048 channels
    int u = threadIdx.x;                 // unit (8 channels) within seg
    int c8 = seg * 2048 + u * 8;
    int row0 = grp * CROWS_;             // groups never cross batch
    int l0 = row0 & (L_ - 1);

    float wv[K_][8], bias[8];
    {
      const float4* wp = (const float4*)(cw + (size_t)c8 * K_);
#pragma unroll
      for (int c = 0; c < 8; ++c) {
        float4 w4 = wp[c];
        wv[0][c] = w4.x; wv[1][c] = w4.y; wv[2][c] = w4.z; wv[3][c] = w4.w;
      }
      float4 b0 = *(const float4*)(cb + c8);
      float4 b1 = *(const float4*)(cb + c8 + 4);
      bias[0] = b0.x; bias[1] = b0.y; bias[2] = b0.z; bias[3] = b0.w;
      bias[4] = b1.x; bias[5] = b1.y; bias[6] = b1.z; bias[7] = b1.w;
    }
    const ushort_t* xin = zb + (size_t)row0 * ZSTR_ + INTER_ + c8;
    ushort_t* xout = xcb + (size_t)row0 * CONVD_ + c8;

    float win[4][8];
#pragma unroll
    for (int i = 0; i < 3; ++i) {
      if (l0 > 0) {
        ld_bf8(xin + (ptrdiff_t)(i - 3) * ZSTR_, win[i]);
      } else {
#pragma unroll
        for (int c = 0; c < 8; ++c) win[i][c] = 0.f;   // zero-pad (matches ref)
      }
    }
#pragma unroll
    for (int r = 0; r < CROWS_; ++r) {
      ld_bf8(xin + (size_t)r * ZSTR_, win[(r + 3) & 3]);
      float a[8];
#pragma unroll
      for (int c = 0; c < 8; ++c) {
        float v = bias[c];
        v = fmaf(wv[0][c], win[(r + 0) & 3][c], v);
        v = fmaf(wv[1][c], win[(r + 1) & 3][c], v);
        v = fmaf(wv[2][c], win[(r + 2) & 3][c], v);
        v = fmaf(wv[3][c], win[(r + 3) & 3][c], v);
        a[c] = v / (1.f + __expf(-v));
      }
      st_bf8(xout + (size_t)r * CONVD_, a);
    }
  } else {
    // ---- dt: softplus + per-chunk cumsum ----
    int bzh = bid - 1536;
    int h = bzh & 63, z = (bzh >> 6) & 7, b = bzh >> 9;
    int i = threadIdx.x;
    size_t row = (size_t)b * L_ + z * CS_ + i;
    float dv = dtraw[(size_t)h * ML_ + row] + dt_bias[h];
    float sp = (dv > 20.f) ? dv : log1pf(expf(dv));
    float v = sp * (-expf(A_log[h]));
    sm[i] = v;
    __syncthreads();
    for (int off = 1; off < 256; off <<= 1) {
      float add = (i >= off) ? sm[i - off] : 0.f;
      __syncthreads();
      sm[i] += add;
      __syncthreads();
    }
    float cs = sm[i];
    size_t ob = ((size_t)b * H_ + h) * L_ + z * CS_ + i;
    dtp[ob] = sp;
    dacs[ob] = cs;
    if (i == CS_ - 1) cdec[bzh] = expf(cs);
  }
}

// ---------------------------------------------------------------------------
// CB[i,j] = sum_n C[i,n]*B[j,n], lower-triangular 64x64 tiles. bf16 out.
// grid (10, 128): tp enumerates the 10 lower-triangular (it,jt) pairs.
// ---------------------------------------------------------------------------
__global__ __launch_bounds__(256) void cb_k(const ushort_t* __restrict__ xcb,
                                            ushort_t* __restrict__ CBo) {
  static const unsigned char itab[10] = {0, 1, 1, 2, 2, 2, 3, 3, 3, 3};
  static const unsigned char jtab[10] = {0, 0, 1, 0, 1, 2, 0, 1, 2, 3};
  int tp = blockIdx.x;
  int it = itab[tp], jt = jtab[tp];
  int bzg = blockIdx.y;
  int g = bzg & 7, z = (bzg >> 3) & 7, b = bzg >> 6;
  int t = threadIdx.x;
  int tx = t & 15, ty = t >> 4;
  __shared__ float CtT[64][68];
  __shared__ float BtT[64][68];
  size_t rowbase = (size_t)b * L_ + (size_t)z * CS_;
  float acc[4][4];
#pragma unroll
  for (int i = 0; i < 4; ++i)
#pragma unroll
    for (int j = 0; j < 4; ++j) acc[i][j] = 0.f;

  for (int half = 0; half < 2; ++half) {
    int nb = half * 64;
    __syncthreads();
#pragma unroll
    for (int u = 0; u < 2; ++u) {
      int idx = t + u * 256;
      int rr = idx >> 3, f = idx & 7;
      float cv[8], bv[8];
      ld_bf8(xcb + (rowbase + it * 64 + rr) * CONVD_ + INTER_ + G_ * N_ + g * N_ + nb + f * 8, cv);
      ld_bf8(xcb + (rowbase + jt * 64 + rr) * CONVD_ + INTER_ + g * N_ + nb + f * 8, bv);
#pragma unroll
      for (int c = 0; c < 8; ++c) { CtT[f * 8 + c][rr] = cv[c]; BtT[f * 8 + c][rr] = bv[c]; }
    }
    __syncthreads();
    for (int n = 0; n < 64; ++n) {
      float4 cv = *(const float4*)&CtT[n][ty * 4];
      float4 bv = *(const float4*)&BtT[n][tx * 4];
      float cc[4] = {cv.x, cv.y, cv.z, cv.w};
      float bb[4] = {bv.x, bv.y, bv.z, bv.w};
#pragma unroll
      for (int i = 0; i < 4; ++i)
#pragma unroll
        for (int j = 0; j < 4; ++j) acc[i][j] = fmaf(cc[i], bb[j], acc[i][j]);
    }
  }
  size_t cbase = ((size_t)((b * 8 + z) * 8 + g)) * (CS_ * CS_);
#pragma unroll
  for (int i = 0; i < 4; ++i) {
    int row = it * 64 + ty * 4 + i;
    ushort4 v;
    v.x = f2b(acc[i][0]); v.y = f2b(acc[i][1]); v.z = f2b(acc[i][2]); v.w = f2b(acc[i][3]);
    *(ushort4*)(CBo + cbase + (size_t)row * CS_ + jt * 64 + tx * 4) = v;
  }
}

// ---------------------------------------------------------------------------
// states (MFMA): S[p,n] = sum_j x[j,p]*w[j]*B[j,n] per (b,z,h).
// ---------------------------------------------------------------------------
__global__ __launch_bounds__(256) void states_mfma(const ushort_t* __restrict__ xcb,
                                                   const float* __restrict__ dacs,
                                                   const float* __restrict__ dtp,
                                                   float* __restrict__ st) {
  int bzh = blockIdx.x;
  int h = bzh & 63, z = (bzh >> 6) & 7, b = bzh >> 9;
  int g = h >> 3;
  int t = threadIdx.x;
  int wv = t >> 6, lane = t & 63;
  int ml = lane & 15, ko = (lane >> 4) * 8;
  __shared__ float ws[256];
  __shared__ __align__(16) ushort_t Xw[64 * 136];    // (w*x)^T [p][j_half]
  __shared__ __align__(16) ushort_t Bt[128 * 136];   // B^T [n][j_half]
  size_t base = ((size_t)b * H_ + h) * L_ + z * CS_;
  float dlast = dacs[base + CS_ - 1];
  ws[t] = __expf(dlast - dacs[base + t]) * dtp[base + t];
  size_t rowbase = (size_t)b * L_ + z * CS_;
  f32x4 acc[4][2];
#pragma unroll
  for (int i = 0; i < 4; ++i) {
    acc[i][0] = (f32x4){0.f, 0.f, 0.f, 0.f};
    acc[i][1] = (f32x4){0.f, 0.f, 0.f, 0.f};
  }
  for (int half = 0; half < 2; ++half) {
    int j0 = half * 128;
    __syncthreads();
    {   // stage Xw: x[j][p]*w[j] -> Xw[p][jl]
      int jl = t >> 1, pseg = (t & 1) * 32;
      const ushort_t* xr = xcb + (rowbase + j0 + jl) * CONVD_ + h * P_ + pseg;
      float wj = ws[j0 + jl];
#pragma unroll
      for (int q = 0; q < 4; ++q) {
        float v[8];
        ld_bf8(xr + q * 8, v);
#pragma unroll
        for (int c = 0; c < 8; ++c) Xw[(pseg + q * 8 + c) * 136 + jl] = f2b(v[c] * wj);
      }
    }
    {   // stage Bt: B[j][n] -> Bt[n][jl]
      int jl = t >> 1, nseg = (t & 1) * 64;
      const ushort_t* br = xcb + (rowbase + j0 + jl) * CONVD_ + INTER_ + g * N_ + nseg;
#pragma unroll
      for (int q = 0; q < 8; ++q) {
        uint4 raw = *(const uint4*)(br + q * 8);
        const ushort_t* s = (const ushort_t*)&raw;
#pragma unroll
        for (int c = 0; c < 8; ++c) Bt[(nseg + q * 8 + c) * 136 + jl] = s[c];
      }
    }
    __syncthreads();
#pragma unroll
    for (int k0 = 0; k0 < 128; k0 += 32) {
      short8 af[4], bf2[2];
#pragma unroll
      for (int mf = 0; mf < 4; ++mf)
        af[mf] = *(const short8*)(Xw + (mf * 16 + ml) * 136 + k0 + ko);
#pragma unroll
      for (int nf = 0; nf < 2; ++nf)
        bf2[nf] = *(const short8*)(Bt + (wv * 32 + nf * 16 + ml) * 136 + k0 + ko);
#pragma unroll
      for (int mf = 0; mf < 4; ++mf)
#pragma unroll
        for (int nf = 0; nf < 2; ++nf)
          acc[mf][nf] = __builtin_amdgcn_mfma_f32_16x16x32_bf16(af[mf], bf2[nf], acc[mf][nf], 0, 0, 0);
    }
  }
  float* outp = st + ((size_t)((b * 8 + z) * H_ + h)) * (P_ * N_);
  int quad = lane >> 4;
#pragma unroll
  for (int mf = 0; mf < 4; ++mf)
#pragma unroll
    for (int nf = 0; nf < 2; ++nf) {
      int n = wv * 32 + nf * 16 + ml;
#pragma unroll
      for (int r = 0; r < 4; ++r) {
        int p = mf * 16 + quad * 4 + r;
        outp[(size_t)p * N_ + n] = acc[mf][nf][r];
      }
    }
}

// ---------------------------------------------------------------------------
// Inter-chunk exclusive scan over nc=8 chunks, IN PLACE on st.
// ---------------------------------------------------------------------------
__global__ __launch_bounds__(256) void scan_k(float* __restrict__ st,
                                              const float* __restrict__ cdec) {
  size_t idx = (size_t)blockIdx.x * 256 + threadIdx.x;
  int b = (int)(idx >> 19);            // 524288 = H_*P_*N_
  size_t rem = idx & 524287;
  int h = (int)(rem >> 13);            // 8192 = P_*N_
  float S = 0.f;
#pragma unroll
  for (int z = 0; z < NC_; ++z) {
    size_t off = (size_t)(b * 8 + z) * 524288 + rem;
    float old = st[off];
    st[off] = S;
    S = cdec[(b * 8 + z) * H_ + h] * S + old;
  }
}

// ---------------------------------------------------------------------------
// y (MFMA): Y^T[p][i] = exp(dA_i)*(prev@C^T) + M@x^T, + D*x, per (b,z,h).
// ---------------------------------------------------------------------------
__global__ __launch_bounds__(256) void y_mfma(const ushort_t* xcb,
                                              const ushort_t* __restrict__ CB,
                                              const float* __restrict__ pv,
                                              const float* __restrict__ dacs,
                                              const float* __restrict__ dtp,
                                              const float* __restrict__ Dw,
                                              ushort_t* Yx) {
  int bzh = blockIdx.x;
  int h = bzh & 63, z = (bzh >> 6) & 7, b = bzh >> 9;
  int g = h >> 3;
  int t = threadIdx.x;
  int wv = t >> 6, lane = t & 63;
  int ml = lane & 15, quad = lane >> 4, ko = quad * 8;
  __shared__ __align__(16) ushort_t Ms[256 * 40];    // Phase B M; Phase A Cs[256*32]
  __shared__ __align__(16) ushort_t XsYs[18432];     // Xs [64][264]; epilogue Ys [256][72]
  __shared__ __align__(16) ushort_t Ps[64 * 136];    // prev bf16 [p][n]
  __shared__ float dAs[256], dts[256];

  size_t rowbase = (size_t)b * L_ + z * CS_;
  {
    size_t base = ((size_t)b * H_ + h) * L_ + z * CS_;
    dAs[t] = dacs[base + t];
    dts[t] = dtp[base + t];
  }
  {   // stage prev fp32 -> bf16 Ps[p][n] (pad 136)
    int p = t >> 2, c0 = (t & 3) * 32;
    const float* pr = pv + ((size_t)((b * 8 + z) * H_ + h)) * (P_ * N_) + (size_t)p * N_ + c0;
    ushort_t* dst = Ps + p * 136 + c0;
#pragma unroll
    for (int u = 0; u < 4; ++u) {
      float4 a = *(const float4*)(pr + u * 8);
      float4 bq = *(const float4*)(pr + u * 8 + 4);
      float v[8] = {a.x, a.y, a.z, a.w, bq.x, bq.y, bq.z, bq.w};
      st_bf8(dst + u * 8, v);
    }
  }
  {   // stage Xs = x^T: read x[i=t][0..63], scatter to Xs[p][t]
    const ushort_t* xr = xcb + (rowbase + t) * CONVD_ + h * P_;
    ushort_t* Xs = XsYs;
#pragma unroll
    for (int q = 0; q < 8; ++q) {
      uint4 raw = *(const uint4*)(xr + q * 8);
      const ushort_t* s = (const ushort_t*)&raw;
#pragma unroll
      for (int c = 0; c < 8; ++c) Xs[(q * 8 + c) * 264 + t] = s[c];
    }
  }

  f32x4 acc[4][4];
#pragma unroll
  for (int i = 0; i < 4; ++i)
#pragma unroll
    for (int j = 0; j < 4; ++j) acc[i][j] = (f32x4){0.f, 0.f, 0.f, 0.f};

  // ---- Phase A: Y_off^T[p][i] = sum_n prev[p][n] * C[i][n]
  int cOff = INTER_ + G_ * N_ + g * N_;
#pragma unroll
  for (int k0 = 0; k0 < 128; k0 += 32) {
    __syncthreads();
#pragma unroll
    for (int u = 0; u < 4; ++u) {   // stage Cs tile [256][32] via global_load_lds
      int sid = u * 256 + t;
      int row = sid >> 2, kc = (sid & 3) * 8;
      gl_lds16(xcb + (rowbase + row) * CONVD_ + cOff + k0 + kc,
               Ms + (size_t)(u * 256 + wv * 64) * 8);
    }
    __syncthreads();
    short8 af[4], bf[4];
#pragma unroll
    for (int mf = 0; mf < 4; ++mf)
      af[mf] = *(const short8*)(Ps + (mf * 16 + ml) * 136 + k0 + ko);
#pragma unroll
    for (int nf = 0; nf < 4; ++nf)
      bf[nf] = *(const short8*)(Ms + (wv * 64 + nf * 16 + ml) * 32 + ko);
#pragma unroll
    for (int mf = 0; mf < 4; ++mf)
#pragma unroll
      for (int nf = 0; nf < 4; ++nf)
        acc[mf][nf] = __builtin_amdgcn_mfma_f32_16x16x32_bf16(af[mf], bf[nf], acc[mf][nf], 0, 0, 0);
  }
  // scale by exp(dA_i), i = column index
#pragma unroll
  for (int nf = 0; nf < 4; ++nf) {
    float e = __expf(dAs[wv * 64 + nf * 16 + ml]);
#pragma unroll
    for (int mf = 0; mf < 4; ++mf) {
      acc[mf][nf][0] *= e; acc[mf][nf][1] *= e;
      acc[mf][nf][2] *= e; acc[mf][nf][3] *= e;
    }
  }

  // ---- Phase B: Y_diag^T[p][i] = sum_j M[i][j] * x[j][p]
  float dAi_t = dAs[t];
  size_t cbase = ((size_t)((b * 8 + z) * 8 + g)) * (CS_ * CS_) + (size_t)t * CS_;
  const ushort_t* Xs = XsYs;
  for (int j0 = 0; j0 < 256; j0 += 32) {
    __syncthreads();
    {   // build M row i=t, cols j0..j0+31 into Ms[t][0..31] (stride 40)
      const ushort_t* cbr = CB + cbase + j0;
      ushort_t* mrow = Ms + t * 40;
#pragma unroll
      for (int q = 0; q < 4; ++q) {
        float cv[8], o[8];
        ld_bf8(cbr + q * 8, cv);
#pragma unroll
        for (int c = 0; c < 8; ++c) {
          int j = j0 + q * 8 + c;
          float m = cv[c] * __expf(dAi_t - dAs[j]) * dts[j];
          o[c] = (j <= t) ? m : 0.f;
        }
        st_bf8(mrow + q * 8, o);
      }
    }
    __syncthreads();
    short8 af[4], bf[4];
#pragma unroll
    for (int mf = 0; mf < 4; ++mf)
      af[mf] = *(const short8*)(Xs + (mf * 16 + ml) * 264 + j0 + ko);
#pragma unroll
    for (int nf = 0; nf < 4; ++nf)
      bf[nf] = *(const short8*)(Ms + (wv * 64 + nf * 16 + ml) * 40 + ko);
#pragma unroll
    for (int mf = 0; mf < 4; ++mf)
#pragma unroll
      for (int nf = 0; nf < 4; ++nf)
        acc[mf][nf] = __builtin_amdgcn_mfma_f32_16x16x32_bf16(af[mf], bf[nf], acc[mf][nf], 0, 0, 0);
  }

  // ---- Epilogue: transpose acc through LDS (Ys over Xs), +D*x, store
  __syncthreads();
  ushort_t* Ys = XsYs;   // [256][72]
#pragma unroll
  for (int mf = 0; mf < 4; ++mf)
#pragma unroll
    for (int nf = 0; nf < 4; ++nf) {
      int iw = wv * 64 + nf * 16 + ml;
      int pb = mf * 16 + quad * 4;
      uint2 pk;
      ushort_t* s = (ushort_t*)&pk;
      s[0] = f2b(acc[mf][nf][0]); s[1] = f2b(acc[mf][nf][1]);
      s[2] = f2b(acc[mf][nf][2]); s[3] = f2b(acc[mf][nf][3]);
      *(uint2*)(Ys + iw * 72 + pb) = pk;
    }
  __syncthreads();
  {
    float Dh = Dw[h];
    const ushort_t* xr = xcb + (rowbase + t) * CONVD_ + h * P_;
    ushort_t* yr = Yx + (rowbase + t) * CONVD_ + h * P_;
#pragma unroll
    for (int q = 0; q < 8; ++q) {
      float xv[8], yv[8], o[8];
      ld_bf8(xr + q * 8, xv);
      ld_bf8(Ys + t * 72 + q * 8, yv);
#pragma unroll
      for (int c = 0; c < 8; ++c) o[c] = yv[c] + Dh * xv[c];
      st_bf8(yr + q * 8, o);
    }
  }
}

// ---------------------------------------------------------------------------
// Fused launch: blocks [0,4096) RMSNorm + silu(z) gate (in-place on xcb
// x-slice); blocks [4096,8192) cast w_out fp32 -> bf16 (independent work).
// ---------------------------------------------------------------------------
__global__ __launch_bounds__(256) void rms_cast2_k(ushort_t* __restrict__ Y,
                                                   const ushort_t* __restrict__ zb,
                                                   const float* __restrict__ nw,
                                                   const float* __restrict__ w_out,
                                                   ushort_t* __restrict__ w_outb) {
  __shared__ float red[4];
  int bid = blockIdx.x;
  int t = threadIdx.x;
  if (bid >= ML_) {
    size_t e8 = ((size_t)(bid - ML_) * 256 + t) * 8;
    float4 a = *(const float4*)(w_out + e8);
    float4 b = *(const float4*)(w_out + e8 + 4);
    float v[8] = {a.x, a.y, a.z, a.w, b.x, b.y, b.z, b.w};
    st_bf8(w_outb + e8, v);
    return;
  }
  int row = bid;
  ushort_t* y = Y + (size_t)row * CONVD_;
  const ushort_t* zp = zb + (size_t)row * ZSTR_;
  float v[2][8];
  float s = 0.f;
#pragma unroll
  for (int u = 0; u < 2; ++u) {
    ld_bf8(y + u * 2048 + t * 8, v[u]);
#pragma unroll
    for (int c = 0; c < 8; ++c) s += v[u][c] * v[u][c];
  }
#pragma unroll
  for (int off = 32; off > 0; off >>= 1) s += __shfl_down(s, off);
  if ((t & 63) == 0) red[t >> 6] = s;
  __syncthreads();
  float tot = red[0] + red[1] + red[2] + red[3];
  float rstd = rsqrtf(tot * (1.f / INTER_) + EPS_);
#pragma unroll
  for (int u = 0; u < 2; ++u) {
    int c0 = u * 2048 + t * 8;
    float zv[8], o[8];
    ld_bf8(zp + c0, zv);
    float4 w0 = *(const float4*)(nw + c0);
    float4 w1 = *(const float4*)(nw + c0 + 4);
    float wv[8] = {w0.x, w0.y, w0.z, w0.w, w1.x, w1.y, w1.z, w1.w};
#pragma unroll
    for (int c = 0; c < 8; ++c)
      o[c] = wv[c] * v[u][c] * rstd * (zv[c] / (1.f + __expf(-zv[c])));
    st_bf8(y + c0, o);
  }
}

// ---------------------------------------------------------------------------
extern "C" void kernel_launch(void* const* d_in, const int* in_sizes, int n_in,
                              void* d_out, int out_size, void* d_ws, size_t ws_size,
                              hipStream_t stream) {
  const float* hs    = (const float*)d_in[0];
  const float* w_in  = (const float*)d_in[1];
  const float* cw    = (const float*)d_in[2];
  const float* cb    = (const float*)d_in[3];
  const float* dtb   = (const float*)d_in[4];
  const float* alog  = (const float*)d_in[5];
  const float* Dw    = (const float*)d_in[6];
  const float* nw    = (const float*)d_in[7];
  const float* w_out = (const float*)d_in[8];
  float* out = (float*)d_out;

  // Workspace layout (~187.3 MiB), regions R1/R2 time-aliased:
  //   R1: hsb [cast1,gemm1] -> cbuf [cb_k..y] -> w_outb [rms_cast2,gemm2]
  //   R2: w_inb [cast1,gemm1] -> st [states..y]
  char* base = (char*)d_ws;
  ushort_t* zb    = (ushort_t*)(base);                         //  83,886,080 B
  ushort_t* xcb   = (ushort_t*)(base + 83886080);              //  50,331,648 B
  float*    dtraw = (float*)(base + 134217728);                //   1,048,576 B
  float*    dtp   = (float*)(base + 135266304);                //   1,048,576 B
  float*    dacs  = (float*)(base + 136314880);                //   1,048,576 B
  float*    cdec  = (float*)(base + 137363456);                //       4,096 B
  char*     R1    = base + 137367552;                          //  16,777,216 B
  char*     R2    = base + 154144768;                          //  42,205,184 B
  ushort_t* hsb    = (ushort_t*)R1;
  ushort_t* cbuf   = (ushort_t*)R1;
  ushort_t* w_outb = (ushort_t*)R1;
  ushort_t* w_inb  = (ushort_t*)R2;
  float*    st     = (float*)R2;

  cast1_k<<<14400, 256, 0, stream>>>(hs, w_in, hsb, w_inb);
  gemm1_256<<<656, 512, 0, stream>>>(hsb, w_inb, zb, dtraw);
  conv_dt_k<<<2560, 256, 0, stream>>>(zb, cw, cb, xcb, dtraw, dtb, alog, dtp, dacs, cdec);
  cb_k<<<dim3(10, B_ * NC_ * G_), 256, 0, stream>>>(xcb, cbuf);
  states_mfma<<<B_ * NC_ * H_, 256, 0, stream>>>(xcb, dacs, dtp, st);
  scan_k<<<(B_ * H_ * P_ * N_) / 256, 256, 0, stream>>>(st, cdec);
  y_mfma<<<B_ * NC_ * H_, 256, 0, stream>>>(xcb, cbuf, st, dacs, dtp, Dw, xcb);
  rms_cast2_k<<<8192, 256, 0, stream>>>(xcb, zb, nw, w_out, w_outb);
  gemm2_128<<<256, 512, 0, stream>>>(xcb, w_outb, out);
}

// Round 6
// 627.346 us; speedup vs baseline: 1.0668x; 1.0036x over previous
//
#include <hip/hip_runtime.h>
#include <hip/hip_bf16.h>
#include <cstdint>
#include <cstddef>

#define H_     64
#define P_     64
#define G_     8
#define N_     128
#define K_     4
#define CS_    256
#define HID_   2048
#define INTER_ 4096
#define CONVD_ 6144
#define PROJ_  10304
#define ZSTR_  10240   /* zb row stride: z + xBC only (dt has fp32 sidecar) */
#define B_     2
#define L_     2048
#define NC_    8
#define ML_    4096    /* B_*L_ */
#define EPS_   1e-5f

typedef unsigned short ushort_t;
typedef __attribute__((ext_vector_type(8))) short short8;
typedef __attribute__((ext_vector_type(4))) float f32x4;

__device__ inline float b2f(ushort_t v) {
  unsigned u = ((unsigned)v) << 16;
  float f;
  __builtin_memcpy(&f, &u, 4);
  return f;
}
__device__ inline ushort_t f2b(float f) {
  unsigned u;
  __builtin_memcpy(&u, &f, 4);
  u = u + 0x7FFFu + ((u >> 16) & 1u);   // round-to-nearest-even
  return (ushort_t)(u >> 16);
}
__device__ inline void ld_bf8(const ushort_t* p, float* f) {
  uint4 u = *(const uint4*)p;
  const ushort_t* s = (const ushort_t*)&u;
#pragma unroll
  for (int c = 0; c < 8; ++c) f[c] = b2f(s[c]);
}
__device__ inline void st_bf8(ushort_t* p, const float* f) {
  uint4 u;
  ushort_t* s = (ushort_t*)&u;
#pragma unroll
  for (int c = 0; c < 8; ++c) s[c] = f2b(f[c]);
  *(uint4*)p = u;
}

// ---------------------------------------------------------------------------
// fp32 -> bf16 cast kernel (hs + w_in)
// ---------------------------------------------------------------------------
__global__ __launch_bounds__(256) void cast1_k(const float* __restrict__ hs,
                                               const float* __restrict__ w_in,
                                               ushort_t* __restrict__ hsb,
                                               ushort_t* __restrict__ w_inb) {
  size_t e8 = ((size_t)blockIdx.x * 256 + threadIdx.x) * 8;
  const float* src;
  ushort_t* dst;
  const size_t HSN = (size_t)ML_ * HID_;          // 8388608
  if (e8 < HSN) { src = hs + e8; dst = hsb + e8; }
  else          { src = w_in + (e8 - HSN); dst = w_inb + (e8 - HSN); }
  float4 a = *(const float4*)src;
  float4 b = *(const float4*)(src + 4);
  float v[8] = {a.x, a.y, a.z, a.w, b.x, b.y, b.z, b.w};
  st_bf8(dst, v);
}

// ---------------------------------------------------------------------------
// global_load_lds helper (16B per lane, wave-uniform LDS base + lane*16)
// ---------------------------------------------------------------------------
typedef const __attribute__((address_space(1))) unsigned int gu32;
typedef __attribute__((address_space(3))) unsigned int lu32;
__device__ __forceinline__ void gl_lds16(const ushort_t* g, ushort_t* l) {
  __builtin_amdgcn_global_load_lds((gu32*)g, (lu32*)l, 16, 0, 0);
}

template<int N> __device__ __forceinline__ void wait_vmcnt() {
  if constexpr (N == 8)      asm volatile("s_waitcnt vmcnt(8)" ::: "memory");
  else if constexpr (N == 6) asm volatile("s_waitcnt vmcnt(6)" ::: "memory");
  else if constexpr (N == 4) asm volatile("s_waitcnt vmcnt(4)" ::: "memory");
  else if constexpr (N == 3) asm volatile("s_waitcnt vmcnt(3)" ::: "memory");
  else                       asm volatile("s_waitcnt vmcnt(0)" ::: "memory");
}

// ---------------------------------------------------------------------------
// MRx256-tile GEMM core (MR = 256 or 128). BK=32, 512 thr = 8 waves (2M x 4N),
// per-wave (MR/2)x64 output ((MR/32)x4 frags of 16x16x32 bf16 MFMA).
// Pipeline: 4-slot LDS ring, DEPTH-3 prefetch (stage tile t+3 while computing
// t). ONE raw s_barrier + one counted vmcnt per K-tile (round-3 proven
// schedule; round-4's 4-barrier phase pacing REGRESSED -20 us, reverted).
// LDS swizzle: stored col-block = logical ^ ((row>>1)&3), applied on the
// pre-swizzled global source (linear gl_lds dest) AND on ds_read addresses.
// ---------------------------------------------------------------------------
template<int MR>
__device__ __forceinline__ void gemm_core(const ushort_t* __restrict__ Ag,
                                          const ushort_t* __restrict__ Bg,
                                          int lda, int ldb, int nkt,
                                          int bm, int bn, int brmax,
                                          ushort_t* __restrict__ As,
                                          ushort_t* __restrict__ Bs,
                                          f32x4 (&acc)[MR / 32][4]) {
  constexpr int MF = MR / 32;            // m-frags per wave (8 or 4)
  constexpr int ASLOT = MR * 32;         // elements per A ring slot
  constexpr int BSLOT = 256 * 32;
  constexpr int LPT = (MR == 256) ? 4 : 3;   // gl_lds issues per tile per wave
  const int t = threadIdx.x;
  const int w = t >> 6, l = t & 63;
  const int wm = w >> 2, wn = w & 3;
  const int ml = l & 15, q = l >> 4;
  const int swz = (ml >> 1) & 3;
  const int aoff = (wm * (MR / 2) + ml) * 32 + ((q ^ swz) << 3);
  const int boff = (wn * 64 + ml) * 32 + ((q ^ swz) << 3);
  // staging: lane l writes stored col-block (l&3) of row base+(l>>2);
  // source logical block = (l&3) ^ ((row>>1)&3) = (l&3) ^ ((l>>3)&3)
  const int permc = (((l & 3) ^ ((l >> 3) & 3)) << 3);
  const ushort_t* ag0 = Ag + (size_t)(bm + (MR / 8) * w + (l >> 2)) * lda + permc;
  const ushort_t* ag1 = ag0 + (size_t)16 * lda;        // MR==256 only
  int br0 = bn + 32 * w + (l >> 2);      if (br0 > brmax) br0 = brmax;
  int br1 = bn + 32 * w + 16 + (l >> 2); if (br1 > brmax) br1 = brmax;
  const ushort_t* bg0 = Bg + (size_t)br0 * ldb + permc;
  const ushort_t* bg1 = Bg + (size_t)br1 * ldb + permc;
  ushort_t* alw = As + ((MR == 256) ? (2 * w * 512) : (w * 512));
  ushort_t* blw = Bs + 2 * w * 512;

#define STAGE_A_(kt_)                                                        \
  { const int k_ = (kt_) << 5;                                               \
    ushort_t* sa_ = alw + ((kt_) & 3) * ASLOT;                               \
    gl_lds16(ag0 + k_, sa_);                                                 \
    if (MR == 256) gl_lds16(ag1 + k_, sa_ + 512); }
#define STAGE_B_(kt_)                                                        \
  { const int k_ = (kt_) << 5;                                               \
    ushort_t* sb_ = blw + ((kt_) & 3) * BSLOT;                               \
    gl_lds16(bg0 + k_, sb_);                                                 \
    gl_lds16(bg1 + k_, sb_ + 512); }

  // prologue: stage tiles 0,1,2 (nkt >= 3 always here)
  STAGE_A_(0); STAGE_B_(0);
  STAGE_A_(1); STAGE_B_(1);
  STAGE_A_(2); STAGE_B_(2);

#pragma unroll
  for (int i = 0; i < MF; ++i)
#pragma unroll
    for (int j = 0; j < 4; ++j) acc[i][j] = (f32x4){0.f, 0.f, 0.f, 0.f};

#pragma unroll 1
  for (int kt = 0; kt < nkt; ++kt) {
    const ushort_t* Asl = As + (kt & 3) * ASLOT;
    const ushort_t* Bsl = Bs + (kt & 3) * BSLOT;
    // tiles kt+1,kt+2 may be in flight (2*LPT loads); all older must be done
    if (kt + 2 < nkt)      wait_vmcnt<2 * LPT>();
    else if (kt + 1 < nkt) wait_vmcnt<LPT>();
    else                   wait_vmcnt<0>();
    __builtin_amdgcn_s_barrier();
    asm volatile("" ::: "memory");
    const bool st = (kt + 3) < nkt;
    short8 bfr[4], af[MF / 2];
#pragma unroll
    for (int nf = 0; nf < 4; ++nf)
      bfr[nf] = *(const short8*)(Bsl + boff + nf * 512);
#pragma unroll
    for (int mf = 0; mf < MF / 2; ++mf)
      af[mf] = *(const short8*)(Asl + aoff + mf * 512);
    if (st) STAGE_A_(kt + 3);
    __builtin_amdgcn_s_setprio(1);
#pragma unroll
    for (int mf = 0; mf < MF / 2; ++mf)
#pragma unroll
      for (int nf = 0; nf < 4; ++nf)
        acc[mf][nf] = __builtin_amdgcn_mfma_f32_16x16x32_bf16(af[mf], bfr[nf], acc[mf][nf], 0, 0, 0);
    __builtin_amdgcn_s_setprio(0);
#pragma unroll
    for (int mf = 0; mf < MF / 2; ++mf)
      af[mf] = *(const short8*)(Asl + aoff + (mf + MF / 2) * 512);
    if (st) STAGE_B_(kt + 3);
    __builtin_amdgcn_s_setprio(1);
#pragma unroll
    for (int mf = 0; mf < MF / 2; ++mf)
#pragma unroll
      for (int nf = 0; nf < 4; ++nf)
        acc[mf + MF / 2][nf] = __builtin_amdgcn_mfma_f32_16x16x32_bf16(af[mf], bfr[nf], acc[mf + MF / 2][nf], 0, 0, 0);
    __builtin_amdgcn_s_setprio(0);
  }
#undef STAGE_A_
#undef STAGE_B_
}

// GEMM1 main: M=4096, N=10496 (z cols 0..10239, dt cols 10240..10303 fp32
// TRANSPOSED to dtraw[64][4096]; cols 10304..10495 garbage/discarded; B rows
// clamped). grid 656 = 16m x 41n.
__global__ __launch_bounds__(512, 2) void gemm1_256(const ushort_t* __restrict__ hsb,
                                                    const ushort_t* __restrict__ w_inb,
                                                    ushort_t* __restrict__ zb,
                                                    float* __restrict__ dtraw) {
  __shared__ __align__(16) ushort_t As[4 * 8192];
  __shared__ __align__(16) ushort_t Bs[4 * 8192];
  int bid = blockIdx.x;
  int wg = (bid & 7) * 82 + (bid >> 3);          // bijective XCD swizzle (656%8==0)
  int tm = wg & 15, tn = wg >> 4;                // tm in [0,16), tn in [0,41)
  int bm = tm * 256, bn = tn * 256;
  f32x4 acc[8][4];
  gemm_core<256>(hsb, w_inb, HID_, HID_, HID_ / 32, bm, bn, PROJ_ - 1, As, Bs, acc);
  int t = threadIdx.x, w = t >> 6, l = t & 63;
  int wm = w >> 2, wn = w & 3, ml = l & 15, quad = l >> 4;
  int rb = bm + wm * 128 + quad * 4;
  int cb = bn + wn * 64 + ml;
  if (tn < 40) {
#pragma unroll
    for (int mf = 0; mf < 8; ++mf)
#pragma unroll
      for (int r = 0; r < 4; ++r) {
        size_t row = (size_t)(rb + mf * 16 + r) * ZSTR_;
#pragma unroll
        for (int nf = 0; nf < 4; ++nf)
          zb[row + cb + nf * 16] = f2b(acc[mf][nf][r]);
      }
  } else if (wn == 0) {   // dt columns, transposed store: dtraw[h][token]
#pragma unroll
    for (int mf = 0; mf < 8; ++mf)
#pragma unroll
      for (int r = 0; r < 4; ++r) {
        int tok = rb + mf * 16 + r;
#pragma unroll
        for (int nf = 0; nf < 4; ++nf)
          dtraw[(size_t)(ml + nf * 16) * ML_ + tok] = acc[mf][nf][r];
      }
  }
}

// GEMM2: out = Y @ out_proj_w^T. M=4096, N=2048, K=4096.
// 128x256 tiles -> grid 256 = 32m x 8n = exactly one full round of the GPU.
__global__ __launch_bounds__(512, 2) void gemm2_128(const ushort_t* __restrict__ Ab,
                                                    const ushort_t* __restrict__ Bb,
                                                    float* __restrict__ C) {
  __shared__ __align__(16) ushort_t As[4 * 4096];
  __shared__ __align__(16) ushort_t Bs[4 * 8192];
  int bid = blockIdx.x;
  int wg = (bid & 7) * 32 + (bid >> 3);          // 256%8==0
  int tm = wg & 31, tn = wg >> 5;
  int bm = tm * 128, bn = tn * 256;
  f32x4 acc[4][4];
  gemm_core<128>(Ab, Bb, CONVD_, INTER_, INTER_ / 32, bm, bn, HID_ - 1, As, Bs, acc);
  int t = threadIdx.x, w = t >> 6, l = t & 63;
  int wm = w >> 2, wn = w & 3, ml = l & 15, quad = l >> 4;
  int rb = bm + wm * 64 + quad * 4;
  int cb = bn + wn * 64 + ml;
#pragma unroll
  for (int mf = 0; mf < 4; ++mf)
#pragma unroll
    for (int r = 0; r < 4; ++r) {
      size_t row = (size_t)(rb + mf * 16 + r) * HID_;
#pragma unroll
      for (int nf = 0; nf < 4; ++nf)
        C[row + cb + nf * 16] = acc[mf][nf][r];
    }
}

// ---------------------------------------------------------------------------
// Fused launch: blocks [0,1536) causal depthwise conv (K=4)+SiLU;
// blocks [1536,2560) dt softplus+cumsum (reads TRANSPOSED dtraw -> coalesced).
// ---------------------------------------------------------------------------
#define CROWS_ 8
__global__ __launch_bounds__(256) void conv_dt_k(const ushort_t* __restrict__ zb,
                                                 const float* __restrict__ cw,
                                                 const float* __restrict__ cb,
                                                 ushort_t* __restrict__ xcb,
                                                 const float* __restrict__ dtraw,
                                                 const float* __restrict__ dt_bias,
                                                 const float* __restrict__ A_log,
                                                 float* __restrict__ dtp,
                                                 float* __restrict__ dacs,
                                                 float* __restrict__ cdec) {
  __shared__ float sm[256];
  int bid = blockIdx.x;
  if (bid < 1536) {
    // ---- conv + SiLU ----
    int grp = bid & 511;                 // ML_/CROWS_ = 512 row groups
    int seg = bid >> 9;                  // 3 segs x 2048 channels
    int u = threadIdx.x;                 // unit (8 channels) within seg
    int c8 = seg * 2048 + u * 8;
    int row0 = grp * CROWS_;             // groups never cross batch
    int l0 = row0 & (L_ - 1);

    float wv[K_][8], bias[8];
    {
      const float4* wp = (const float4*)(cw + (size_t)c8 * K_);
#pragma unroll
      for (int c = 0; c < 8; ++c) {
        float4 w4 = wp[c];
        wv[0][c] = w4.x; wv[1][c] = w4.y; wv[2][c] = w4.z; wv[3][c] = w4.w;
      }
      float4 b0 = *(const float4*)(cb + c8);
      float4 b1 = *(const float4*)(cb + c8 + 4);
      bias[0] = b0.x; bias[1] = b0.y; bias[2] = b0.z; bias[3] = b0.w;
      bias[4] = b1.x; bias[5] = b1.y; bias[6] = b1.z; bias[7] = b1.w;
    }
    const ushort_t* xin = zb + (size_t)row0 * ZSTR_ + INTER_ + c8;
    ushort_t* xout = xcb + (size_t)row0 * CONVD_ + c8;

    float win[4][8];
#pragma unroll
    for (int i = 0; i < 3; ++i) {
      if (l0 > 0) {
        ld_bf8(xin + (ptrdiff_t)(i - 3) * ZSTR_, win[i]);
      } else {
#pragma unroll
        for (int c = 0; c < 8; ++c) win[i][c] = 0.f;   // zero-pad (matches ref)
      }
    }
#pragma unroll
    for (int r = 0; r < CROWS_; ++r) {
      ld_bf8(xin + (size_t)r * ZSTR_, win[(r + 3) & 3]);
      float a[8];
#pragma unroll
      for (int c = 0; c < 8; ++c) {
        float v = bias[c];
        v = fmaf(wv[0][c], win[(r + 0) & 3][c], v);
        v = fmaf(wv[1][c], win[(r + 1) & 3][c], v);
        v = fmaf(wv[2][c], win[(r + 2) & 3][c], v);
        v = fmaf(wv[3][c], win[(r + 3) & 3][c], v);
        a[c] = v / (1.f + __expf(-v));
      }
      st_bf8(xout + (size_t)r * CONVD_, a);
    }
  } else {
    // ---- dt: softplus + per-chunk cumsum ----
    int bzh = bid - 1536;
    int h = bzh & 63, z = (bzh >> 6) & 7, b = bzh >> 9;
    int i = threadIdx.x;
    size_t row = (size_t)b * L_ + z * CS_ + i;
    float dv = dtraw[(size_t)h * ML_ + row] + dt_bias[h];
    float sp = (dv > 20.f) ? dv : log1pf(expf(dv));
    float v = sp * (-expf(A_log[h]));
    sm[i] = v;
    __syncthreads();
    for (int off = 1; off < 256; off <<= 1) {
      float add = (i >= off) ? sm[i - off] : 0.f;
      __syncthreads();
      sm[i] += add;
      __syncthreads();
    }
    float cs = sm[i];
    size_t ob = ((size_t)b * H_ + h) * L_ + z * CS_ + i;
    dtp[ob] = sp;
    dacs[ob] = cs;
    if (i == CS_ - 1) cdec[bzh] = expf(cs);
  }
}

// ---------------------------------------------------------------------------
// CB[i,j] = sum_n C[i,n]*B[j,n], lower-triangular 64x64 tiles. bf16 out.
// MFMA version: stage C-tile/B-tile [64][128] bf16 via gl_lds with a
// 16-block XOR swizzle (stored blk = logical ^ (row&15); source-permuted,
// read-matched), then 16 MFMA per wave. grid (10, 128).
// ---------------------------------------------------------------------------
__global__ __launch_bounds__(256) void cb_k(const ushort_t* __restrict__ xcb,
                                            ushort_t* __restrict__ CBo) {
  static const unsigned char itab[10] = {0, 1, 1, 2, 2, 2, 3, 3, 3, 3};
  static const unsigned char jtab[10] = {0, 0, 1, 0, 1, 2, 0, 1, 2, 3};
  int tp = blockIdx.x;
  int it = itab[tp], jt = jtab[tp];
  int bzg = blockIdx.y;
  int g = bzg & 7, z = (bzg >> 3) & 7, b = bzg >> 6;
  int t = threadIdx.x;
  int w = t >> 6, l = t & 63;
  __shared__ __align__(16) ushort_t Cs[64 * 128];
  __shared__ __align__(16) ushort_t Bs[64 * 128];
  size_t rowbase = (size_t)b * L_ + (size_t)z * CS_;
  {   // stage: wave w covers rows 16w..16w+15, 4 rows per gl_lds issue
    int s = l & 15;                        // stored 16B block within row
    int cO = INTER_ + G_ * N_ + g * N_;
    int bO = INTER_ + g * N_;
#pragma unroll
    for (int i = 0; i < 4; ++i) {
      int row = 16 * w + 4 * i + (l >> 4); // local row this lane writes
      int src = ((s ^ (row & 15)) << 3);   // pre-swizzled source col (elems)
      gl_lds16(xcb + (rowbase + it * 64 + row) * CONVD_ + cO + src,
               Cs + (16 * w + 4 * i) * 128);
      gl_lds16(xcb + (rowbase + jt * 64 + row) * CONVD_ + bO + src,
               Bs + (16 * w + 4 * i) * 128);
    }
  }
  asm volatile("s_waitcnt vmcnt(0)" ::: "memory");
  __builtin_amdgcn_s_barrier();
  // wave w -> 32x32 output tile (wm = w>>1, wn = w&1)
  int wm = w >> 1, wn = w & 1;
  int ml = l & 15, q = l >> 4;
  f32x4 acc[2][2];
#pragma unroll
  for (int i = 0; i < 2; ++i)
#pragma unroll
    for (int j = 0; j < 2; ++j) acc[i][j] = (f32x4){0.f, 0.f, 0.f, 0.f};
#pragma unroll
  for (int kk = 0; kk < 4; ++kk) {
    short8 af[2], bf[2];
#pragma unroll
    for (int mf = 0; mf < 2; ++mf) {
      int row = wm * 32 + mf * 16 + ml;
      af[mf] = *(const short8*)(Cs + row * 128 + (((kk * 4 + q) ^ (row & 15)) << 3));
    }
#pragma unroll
    for (int nf = 0; nf < 2; ++nf) {
      int row = wn * 32 + nf * 16 + ml;
      bf[nf] = *(const short8*)(Bs + row * 128 + (((kk * 4 + q) ^ (row & 15)) << 3));
    }
#pragma unroll
    for (int mf = 0; mf < 2; ++mf)
#pragma unroll
      for (int nf = 0; nf < 2; ++nf)
        acc[mf][nf] = __builtin_amdgcn_mfma_f32_16x16x32_bf16(af[mf], bf[nf], acc[mf][nf], 0, 0, 0);
  }
  // epilogue: D col = lane&15 (j), row = (lane>>4)*4 + reg (i)
  size_t cbase = ((size_t)((b * 8 + z) * 8 + g)) * (CS_ * CS_);
#pragma unroll
  for (int mf = 0; mf < 2; ++mf)
#pragma unroll
    for (int nf = 0; nf < 2; ++nf)
#pragma unroll
      for (int r = 0; r < 4; ++r) {
        int i = wm * 32 + mf * 16 + q * 4 + r;
        int j = wn * 32 + nf * 16 + ml;
        CBo[cbase + (size_t)(it * 64 + i) * CS_ + jt * 64 + j] = f2b(acc[mf][nf][r]);
      }
}

// ---------------------------------------------------------------------------
// states (MFMA): S[p,n] = sum_j x[j,p]*w[j]*B[j,n] per (b,z,h).
// Staging writes PAIRED (2 j's per thread -> b32 LDS writes, half the instr).
// ---------------------------------------------------------------------------
__global__ __launch_bounds__(256) void states_mfma(const ushort_t* __restrict__ xcb,
                                                   const float* __restrict__ dacs,
                                                   const float* __restrict__ dtp,
                                                   float* __restrict__ st) {
  int bzh = blockIdx.x;
  int h = bzh & 63, z = (bzh >> 6) & 7, b = bzh >> 9;
  int g = h >> 3;
  int t = threadIdx.x;
  int wv = t >> 6, lane = t & 63;
  int ml = lane & 15, ko = (lane >> 4) * 8;
  __shared__ float ws[256];
  __shared__ __align__(16) ushort_t Xw[64 * 136];    // (w*x)^T [p][j_half]
  __shared__ __align__(16) ushort_t Bt[128 * 136];   // B^T [n][j_half]
  size_t base = ((size_t)b * H_ + h) * L_ + z * CS_;
  float dlast = dacs[base + CS_ - 1];
  ws[t] = __expf(dlast - dacs[base + t]) * dtp[base + t];
  size_t rowbase = (size_t)b * L_ + z * CS_;
  f32x4 acc[4][2];
#pragma unroll
  for (int i = 0; i < 4; ++i) {
    acc[i][0] = (f32x4){0.f, 0.f, 0.f, 0.f};
    acc[i][1] = (f32x4){0.f, 0.f, 0.f, 0.f};
  }
  for (int half = 0; half < 2; ++half) {
    int j0 = half * 128;
    __syncthreads();
    {   // stage Xw: x[j][p]*w[j] -> Xw[p][j], 2 j x 16 p per thread
      int j2 = (t & 63) * 2, pseg = (t >> 6) * 16;
      const ushort_t* xr0 = xcb + (rowbase + j0 + j2) * CONVD_ + h * P_ + pseg;
      const ushort_t* xr1 = xr0 + CONVD_;
      float w0 = ws[j0 + j2], w1 = ws[j0 + j2 + 1];
      float v0[8], v0b[8], v1[8], v1b[8];
      ld_bf8(xr0, v0); ld_bf8(xr0 + 8, v0b);
      ld_bf8(xr1, v1); ld_bf8(xr1 + 8, v1b);
      unsigned* xw32 = (unsigned*)Xw;
      int col = t & 63;                  // u32 column = j2/2
#pragma unroll
      for (int pp = 0; pp < 8; ++pp) {
        unsigned lo = f2b(v0[pp] * w0), hi = f2b(v1[pp] * w1);
        xw32[(pseg + pp) * 68 + col] = lo | (hi << 16);
      }
#pragma unroll
      for (int pp = 0; pp < 8; ++pp) {
        unsigned lo = f2b(v0b[pp] * w0), hi = f2b(v1b[pp] * w1);
        xw32[(pseg + 8 + pp) * 68 + col] = lo | (hi << 16);
      }
    }
    {   // stage Bt: B[j][n] -> Bt[n][j], 2 j x 32 n per thread
      int j2 = (t & 63) * 2, nseg = (t >> 6) * 32;
      const ushort_t* br0 = xcb + (rowbase + j0 + j2) * CONVD_ + INTER_ + g * N_ + nseg;
      const ushort_t* br1 = br0 + CONVD_;
      unsigned* bt32 = (unsigned*)Bt;
      int col = t & 63;
#pragma unroll
      for (int qq = 0; qq < 4; ++qq) {
        uint4 r0 = *(const uint4*)(br0 + qq * 8);
        uint4 r1 = *(const uint4*)(br1 + qq * 8);
        const ushort_t* s0 = (const ushort_t*)&r0;
        const ushort_t* s1 = (const ushort_t*)&r1;
#pragma unroll
        for (int c = 0; c < 8; ++c)
          bt32[(nseg + qq * 8 + c) * 68 + col] = (unsigned)s0[c] | ((unsigned)s1[c] << 16);
      }
    }
    __syncthreads();
#pragma unroll
    for (int k0 = 0; k0 < 128; k0 += 32) {
      short8 af[4], bf2[2];
#pragma unroll
      for (int mf = 0; mf < 4; ++mf)
        af[mf] = *(const short8*)(Xw + (mf * 16 + ml) * 136 + k0 + ko);
#pragma unroll
      for (int nf = 0; nf < 2; ++nf)
        bf2[nf] = *(const short8*)(Bt + (wv * 32 + nf * 16 + ml) * 136 + k0 + ko);
#pragma unroll
      for (int mf = 0; mf < 4; ++mf)
#pragma unroll
        for (int nf = 0; nf < 2; ++nf)
          acc[mf][nf] = __builtin_amdgcn_mfma_f32_16x16x32_bf16(af[mf], bf2[nf], acc[mf][nf], 0, 0, 0);
    }
  }
  float* outp = st + ((size_t)((b * 8 + z) * H_ + h)) * (P_ * N_);
  int quad = lane >> 4;
#pragma unroll
  for (int mf = 0; mf < 4; ++mf)
#pragma unroll
    for (int nf = 0; nf < 2; ++nf) {
      int n = wv * 32 + nf * 16 + ml;
#pragma unroll
      for (int r = 0; r < 4; ++r) {
        int p = mf * 16 + quad * 4 + r;
        outp[(size_t)p * N_ + n] = acc[mf][nf][r];
      }
    }
}

// ---------------------------------------------------------------------------
// Inter-chunk exclusive scan over nc=8 chunks, IN PLACE on st.
// ---------------------------------------------------------------------------
__global__ __launch_bounds__(256) void scan_k(float* __restrict__ st,
                                              const float* __restrict__ cdec) {
  size_t idx = (size_t)blockIdx.x * 256 + threadIdx.x;
  int b = (int)(idx >> 19);            // 524288 = H_*P_*N_
  size_t rem = idx & 524287;
  int h = (int)(rem >> 13);            // 8192 = P_*N_
  float S = 0.f;
#pragma unroll
  for (int z = 0; z < NC_; ++z) {
    size_t off = (size_t)(b * 8 + z) * 524288 + rem;
    float old = st[off];
    st[off] = S;
    S = cdec[(b * 8 + z) * H_ + h] * S + old;
  }
}

// ---------------------------------------------------------------------------
// y (MFMA): Y^T[p][i] = exp(dA_i)*(prev@C^T) + M@x^T, + D*x, per (b,z,h).
// Phase B: CB rows register-prefetched one iteration ahead (T14 split) so
// the uncoalesced global read latency hides under the MFMA cluster.
// ---------------------------------------------------------------------------
__global__ __launch_bounds__(256) void y_mfma(const ushort_t* xcb,
                                              const ushort_t* __restrict__ CB,
                                              const float* __restrict__ pv,
                                              const float* __restrict__ dacs,
                                              const float* __restrict__ dtp,
                                              const float* __restrict__ Dw,
                                              ushort_t* Yx) {
  int bzh = blockIdx.x;
  int h = bzh & 63, z = (bzh >> 6) & 7, b = bzh >> 9;
  int g = h >> 3;
  int t = threadIdx.x;
  int wv = t >> 6, lane = t & 63;
  int ml = lane & 15, quad = lane >> 4, ko = quad * 8;
  __shared__ __align__(16) ushort_t Ms[256 * 40];    // Phase B M; Phase A Cs[256*32]
  __shared__ __align__(16) ushort_t XsYs[18432];     // Xs [64][264]; epilogue Ys [256][72]
  __shared__ __align__(16) ushort_t Ps[64 * 136];    // prev bf16 [p][n]
  __shared__ float dAs[256], dts[256];

  size_t rowbase = (size_t)b * L_ + z * CS_;
  {
    size_t base = ((size_t)b * H_ + h) * L_ + z * CS_;
    dAs[t] = dacs[base + t];
    dts[t] = dtp[base + t];
  }
  {   // stage prev fp32 -> bf16 Ps[p][n] (pad 136)
    int p = t >> 2, c0 = (t & 3) * 32;
    const float* pr = pv + ((size_t)((b * 8 + z) * H_ + h)) * (P_ * N_) + (size_t)p * N_ + c0;
    ushort_t* dst = Ps + p * 136 + c0;
#pragma unroll
    for (int u = 0; u < 4; ++u) {
      float4 a = *(const float4*)(pr + u * 8);
      float4 bq = *(const float4*)(pr + u * 8 + 4);
      float v[8] = {a.x, a.y, a.z, a.w, bq.x, bq.y, bq.z, bq.w};
      st_bf8(dst + u * 8, v);
    }
  }
  {   // stage Xs = x^T: read x[i=t][0..63], scatter to Xs[p][t]
    const ushort_t* xr = xcb + (rowbase + t) * CONVD_ + h * P_;
    ushort_t* Xs = XsYs;
#pragma unroll
    for (int q = 0; q < 8; ++q) {
      uint4 raw = *(const uint4*)(xr + q * 8);
      const ushort_t* s = (const ushort_t*)&raw;
#pragma unroll
      for (int c = 0; c < 8; ++c) Xs[(q * 8 + c) * 264 + t] = s[c];
    }
  }

  f32x4 acc[4][4];
#pragma unroll
  for (int i = 0; i < 4; ++i)
#pragma unroll
    for (int j = 0; j < 4; ++j) acc[i][j] = (f32x4){0.f, 0.f, 0.f, 0.f};

  // ---- Phase A: Y_off^T[p][i] = sum_n prev[p][n] * C[i][n]
  int cOff = INTER_ + G_ * N_ + g * N_;
#pragma unroll
  for (int k0 = 0; k0 < 128; k0 += 32) {
    __syncthreads();
#pragma unroll
    for (int u = 0; u < 4; ++u) {   // stage Cs tile [256][32] via global_load_lds
      int sid = u * 256 + t;
      int row = sid >> 2, kc = (sid & 3) * 8;
      gl_lds16(xcb + (rowbase + row) * CONVD_ + cOff + k0 + kc,
               Ms + (size_t)(u * 256 + wv * 64) * 8);
    }
    __syncthreads();
    short8 af[4], bf[4];
#pragma unroll
    for (int mf = 0; mf < 4; ++mf)
      af[mf] = *(const short8*)(Ps + (mf * 16 + ml) * 136 + k0 + ko);
#pragma unroll
    for (int nf = 0; nf < 4; ++nf)
      bf[nf] = *(const short8*)(Ms + (wv * 64 + nf * 16 + ml) * 32 + ko);
#pragma unroll
    for (int mf = 0; mf < 4; ++mf)
#pragma unroll
      for (int nf = 0; nf < 4; ++nf)
        acc[mf][nf] = __builtin_amdgcn_mfma_f32_16x16x32_bf16(af[mf], bf[nf], acc[mf][nf], 0, 0, 0);
  }
  // scale by exp(dA_i), i = column index
#pragma unroll
  for (int nf = 0; nf < 4; ++nf) {
    float e = __expf(dAs[wv * 64 + nf * 16 + ml]);
#pragma unroll
    for (int mf = 0; mf < 4; ++mf) {
      acc[mf][nf][0] *= e; acc[mf][nf][1] *= e;
      acc[mf][nf][2] *= e; acc[mf][nf][3] *= e;
    }
  }

  // ---- Phase B: Y_diag^T[p][i] = sum_j M[i][j] * x[j][p]
  float dAi_t = dAs[t];
  size_t cbase = ((size_t)((b * 8 + z) * 8 + g)) * (CS_ * CS_) + (size_t)t * CS_;
  const ushort_t* Xs = XsYs;
  uint4 pre[4];
  {
    const ushort_t* cbr = CB + cbase;
#pragma unroll
    for (int qq = 0; qq < 4; ++qq) pre[qq] = *(const uint4*)(cbr + qq * 8);
  }
  for (int j0 = 0; j0 < 256; j0 += 32) {
    __syncthreads();
    {   // build M row i=t, cols j0..j0+31 into Ms[t][0..31] (stride 40)
      ushort_t* mrow = Ms + t * 40;
#pragma unroll
      for (int qq = 0; qq < 4; ++qq) {
        const ushort_t* s = (const ushort_t*)&pre[qq];
        float o[8];
#pragma unroll
        for (int c = 0; c < 8; ++c) {
          int j = j0 + qq * 8 + c;
          float m = b2f(s[c]) * __expf(dAi_t - dAs[j]) * dts[j];
          o[c] = (j <= t) ? m : 0.f;
        }
        st_bf8(mrow + qq * 8, o);
      }
    }
    uint4 nxt[4];
    if (j0 + 32 < 256) {   // issue next iteration's CB loads (hide under MFMA)
      const ushort_t* cbr = CB + cbase + j0 + 32;
#pragma unroll
      for (int qq = 0; qq < 4; ++qq) nxt[qq] = *(const uint4*)(cbr + qq * 8);
    }
    __syncthreads();
    short8 af[4], bf[4];
#pragma unroll
    for (int mf = 0; mf < 4; ++mf)
      af[mf] = *(const short8*)(Xs + (mf * 16 + ml) * 264 + j0 + ko);
#pragma unroll
    for (int nf = 0; nf < 4; ++nf)
      bf[nf] = *(const short8*)(Ms + (wv * 64 + nf * 16 + ml) * 40 + ko);
#pragma unroll
    for (int mf = 0; mf < 4; ++mf)
#pragma unroll
      for (int nf = 0; nf < 4; ++nf)
        acc[mf][nf] = __builtin_amdgcn_mfma_f32_16x16x32_bf16(af[mf], bf[nf], acc[mf][nf], 0, 0, 0);
#pragma unroll
    for (int qq = 0; qq < 4; ++qq) pre[qq] = nxt[qq];
  }

  // ---- Epilogue: transpose acc through LDS (Ys over Xs), +D*x, store
  __syncthreads();
  ushort_t* Ys = XsYs;   // [256][72]
#pragma unroll
  for (int mf = 0; mf < 4; ++mf)
#pragma unroll
    for (int nf = 0; nf < 4; ++nf) {
      int iw = wv * 64 + nf * 16 + ml;
      int pb = mf * 16 + quad * 4;
      uint2 pk;
      ushort_t* s = (ushort_t*)&pk;
      s[0] = f2b(acc[mf][nf][0]); s[1] = f2b(acc[mf][nf][1]);
      s[2] = f2b(acc[mf][nf][2]); s[3] = f2b(acc[mf][nf][3]);
      *(uint2*)(Ys + iw * 72 + pb) = pk;
    }
  __syncthreads();
  {
    float Dh = Dw[h];
    const ushort_t* xr = xcb + (rowbase + t) * CONVD_ + h * P_;
    ushort_t* yr = Yx + (rowbase + t) * CONVD_ + h * P_;
#pragma unroll
    for (int q = 0; q < 8; ++q) {
      float xv[8], yv[8], o[8];
      ld_bf8(xr + q * 8, xv);
      ld_bf8(Ys + t * 72 + q * 8, yv);
#pragma unroll
      for (int c = 0; c < 8; ++c) o[c] = yv[c] + Dh * xv[c];
      st_bf8(yr + q * 8, o);
    }
  }
}

// ---------------------------------------------------------------------------
// Fused launch: blocks [0,4096) RMSNorm + silu(z) gate (in-place on xcb
// x-slice); blocks [4096,8192) cast w_out fp32 -> bf16 (independent work).
// ---------------------------------------------------------------------------
__global__ __launch_bounds__(256) void rms_cast2_k(ushort_t* __restrict__ Y,
                                                   const ushort_t* __restrict__ zb,
                                                   const float* __restrict__ nw,
                                                   const float* __restrict__ w_out,
                                                   ushort_t* __restrict__ w_outb) {
  __shared__ float red[4];
  int bid = blockIdx.x;
  int t = threadIdx.x;
  if (bid >= ML_) {
    size_t e8 = ((size_t)(bid - ML_) * 256 + t) * 8;
    float4 a = *(const float4*)(w_out + e8);
    float4 b = *(const float4*)(w_out + e8 + 4);
    float v[8] = {a.x, a.y, a.z, a.w, b.x, b.y, b.z, b.w};
    st_bf8(w_outb + e8, v);
    return;
  }
  int row = bid;
  ushort_t* y = Y + (size_t)row * CONVD_;
  const ushort_t* zp = zb + (size_t)row * ZSTR_;
  float v[2][8];
  float s = 0.f;
#pragma unroll
  for (int u = 0; u < 2; ++u) {
    ld_bf8(y + u * 2048 + t * 8, v[u]);
#pragma unroll
    for (int c = 0; c < 8; ++c) s += v[u][c] * v[u][c];
  }
#pragma unroll
  for (int off = 32; off > 0; off >>= 1) s += __shfl_down(s, off);
  if ((t & 63) == 0) red[t >> 6] = s;
  __syncthreads();
  float tot = red[0] + red[1] + red[2] + red[3];
  float rstd = rsqrtf(tot * (1.f / INTER_) + EPS_);
#pragma unroll
  for (int u = 0; u < 2; ++u) {
    int c0 = u * 2048 + t * 8;
    float zv[8], o[8];
    ld_bf8(zp + c0, zv);
    float4 w0 = *(const float4*)(nw + c0);
    float4 w1 = *(const float4*)(nw + c0 + 4);
    float wv[8] = {w0.x, w0.y, w0.z, w0.w, w1.x, w1.y, w1.z, w1.w};
#pragma unroll
    for (int c = 0; c < 8; ++c)
      o[c] = wv[c] * v[u][c] * rstd * (zv[c] / (1.f + __expf(-zv[c])));
    st_bf8(y + c0, o);
  }
}

// ---------------------------------------------------------------------------
extern "C" void kernel_launch(void* const* d_in, const int* in_sizes, int n_in,
                              void* d_out, int out_size, void* d_ws, size_t ws_size,
                              hipStream_t stream) {
  const float* hs    = (const float*)d_in[0];
  const float* w_in  = (const float*)d_in[1];
  const float* cw    = (const float*)d_in[2];
  const float* cb    = (const float*)d_in[3];
  const float* dtb   = (const float*)d_in[4];
  const float* alog  = (const float*)d_in[5];
  const float* Dw    = (const float*)d_in[6];
  const float* nw    = (const float*)d_in[7];
  const float* w_out = (const float*)d_in[8];
  float* out = (float*)d_out;

  // Workspace layout (~187.3 MiB), regions R1/R2 time-aliased:
  //   R1: hsb [cast1,gemm1] -> cbuf [cb_k..y] -> w_outb [rms_cast2,gemm2]
  //   R2: w_inb [cast1,gemm1] -> st [states..y]
  char* base = (char*)d_ws;
  ushort_t* zb    = (ushort_t*)(base);                         //  83,886,080 B
  ushort_t* xcb   = (ushort_t*)(base + 83886080);              //  50,331,648 B
  float*    dtraw = (float*)(base + 134217728);                //   1,048,576 B
  float*    dtp   = (float*)(base + 135266304);                //   1,048,576 B
  float*    dacs  = (float*)(base + 136314880);                //   1,048,576 B
  float*    cdec  = (float*)(base + 137363456);                //       4,096 B
  char*     R1    = base + 137367552;                          //  16,777,216 B
  char*     R2    = base + 154144768;                          //  42,205,184 B
  ushort_t* hsb    = (ushort_t*)R1;
  ushort_t* cbuf   = (ushort_t*)R1;
  ushort_t* w_outb = (ushort_t*)R1;
  ushort_t* w_inb  = (ushort_t*)R2;
  float*    st     = (float*)R2;

  cast1_k<<<14400, 256, 0, stream>>>(hs, w_in, hsb, w_inb);
  gemm1_256<<<656, 512, 0, stream>>>(hsb, w_inb, zb, dtraw);
  conv_dt_k<<<2560, 256, 0, stream>>>(zb, cw, cb, xcb, dtraw, dtb, alog, dtp, dacs, cdec);
  cb_k<<<dim3(10, B_ * NC_ * G_), 256, 0, stream>>>(xcb, cbuf);
  states_mfma<<<B_ * NC_ * H_, 256, 0, stream>>>(xcb, dacs, dtp, st);
  scan_k<<<(B_ * H_ * P_ * N_) / 256, 256, 0, stream>>>(st, cdec);
  y_mfma<<<B_ * NC_ * H_, 256, 0, stream>>>(xcb, cbuf, st, dacs, dtp, Dw, xcb);
  rms_cast2_k<<<8192, 256, 0, stream>>>(xcb, zb, nw, w_out, w_outb);
  gemm2_128<<<256, 512, 0, stream>>>(xcb, w_outb, out);
}

// Round 7
// 608.186 us; speedup vs baseline: 1.1004x; 1.0315x over previous
//
#include <hip/hip_runtime.h>
#include <hip/hip_bf16.h>
#include <cstdint>
#include <cstddef>

#define H_     64
#define P_     64
#define G_     8
#define N_     128
#define K_     4
#define CS_    256
#define HID_   2048
#define INTER_ 4096
#define CONVD_ 6144
#define PROJ_  10304
#define ZSTR_  10240   /* zb row stride: z + xBC only (dt has fp32 sidecar) */
#define B_     2
#define L_     2048
#define NC_    8
#define ML_    4096    /* B_*L_ */
#define EPS_   1e-5f

typedef unsigned short ushort_t;
typedef __attribute__((ext_vector_type(8))) short short8;
typedef __attribute__((ext_vector_type(4))) float f32x4;

__device__ inline float b2f(ushort_t v) {
  unsigned u = ((unsigned)v) << 16;
  float f;
  __builtin_memcpy(&f, &u, 4);
  return f;
}
__device__ inline ushort_t f2b(float f) {
  unsigned u;
  __builtin_memcpy(&u, &f, 4);
  u = u + 0x7FFFu + ((u >> 16) & 1u);   // round-to-nearest-even
  return (ushort_t)(u >> 16);
}
__device__ inline void ld_bf8(const ushort_t* p, float* f) {
  uint4 u = *(const uint4*)p;
  const ushort_t* s = (const ushort_t*)&u;
#pragma unroll
  for (int c = 0; c < 8; ++c) f[c] = b2f(s[c]);
}
__device__ inline void st_bf8(ushort_t* p, const float* f) {
  uint4 u;
  ushort_t* s = (ushort_t*)&u;
#pragma unroll
  for (int c = 0; c < 8; ++c) s[c] = f2b(f[c]);
  *(uint4*)p = u;
}

// ---------------------------------------------------------------------------
// fp32 -> bf16 cast kernel (hs + w_in)
// ---------------------------------------------------------------------------
__global__ __launch_bounds__(256) void cast1_k(const float* __restrict__ hs,
                                               const float* __restrict__ w_in,
                                               ushort_t* __restrict__ hsb,
                                               ushort_t* __restrict__ w_inb) {
  size_t e8 = ((size_t)blockIdx.x * 256 + threadIdx.x) * 8;
  const float* src;
  ushort_t* dst;
  const size_t HSN = (size_t)ML_ * HID_;          // 8388608
  if (e8 < HSN) { src = hs + e8; dst = hsb + e8; }
  else          { src = w_in + (e8 - HSN); dst = w_inb + (e8 - HSN); }
  float4 a = *(const float4*)src;
  float4 b = *(const float4*)(src + 4);
  float v[8] = {a.x, a.y, a.z, a.w, b.x, b.y, b.z, b.w};
  st_bf8(dst, v);
}

// ---------------------------------------------------------------------------
// global_load_lds helper (16B per lane, wave-uniform LDS base + lane*16)
// ---------------------------------------------------------------------------
typedef const __attribute__((address_space(1))) unsigned int gu32;
typedef __attribute__((address_space(3))) unsigned int lu32;
__device__ __forceinline__ void gl_lds16(const ushort_t* g, ushort_t* l) {
  __builtin_amdgcn_global_load_lds((gu32*)g, (lu32*)l, 16, 0, 0);
}

template<int N> __device__ __forceinline__ void wait_vmcnt() {
  if constexpr (N == 8)      asm volatile("s_waitcnt vmcnt(8)" ::: "memory");
  else if constexpr (N == 6) asm volatile("s_waitcnt vmcnt(6)" ::: "memory");
  else if constexpr (N == 4) asm volatile("s_waitcnt vmcnt(4)" ::: "memory");
  else if constexpr (N == 3) asm volatile("s_waitcnt vmcnt(3)" ::: "memory");
  else                       asm volatile("s_waitcnt vmcnt(0)" ::: "memory");
}

// ---------------------------------------------------------------------------
// MRx256-tile GEMM core (MR = 256). BK=32, 512 thr = 8 waves (2M x 4N),
// per-wave (MR/2)x64 output. 4-slot LDS ring, DEPTH-3 prefetch, ONE raw
// s_barrier + one counted vmcnt per K-tile (round-3 proven schedule).
// LDS swizzle: stored col-block = logical ^ ((row>>1)&3), applied on the
// pre-swizzled global source (linear gl_lds dest) AND on ds_read addresses.
// ---------------------------------------------------------------------------
template<int MR>
__device__ __forceinline__ void gemm_core(const ushort_t* __restrict__ Ag,
                                          const ushort_t* __restrict__ Bg,
                                          int lda, int ldb, int nkt,
                                          int bm, int bn, int brmax,
                                          ushort_t* __restrict__ As,
                                          ushort_t* __restrict__ Bs,
                                          f32x4 (&acc)[MR / 32][4]) {
  constexpr int MF = MR / 32;            // m-frags per wave (8 or 4)
  constexpr int ASLOT = MR * 32;         // elements per A ring slot
  constexpr int BSLOT = 256 * 32;
  constexpr int LPT = (MR == 256) ? 4 : 3;   // gl_lds issues per tile per wave
  const int t = threadIdx.x;
  const int w = t >> 6, l = t & 63;
  const int wm = w >> 2, wn = w & 3;
  const int ml = l & 15, q = l >> 4;
  const int swz = (ml >> 1) & 3;
  const int aoff = (wm * (MR / 2) + ml) * 32 + ((q ^ swz) << 3);
  const int boff = (wn * 64 + ml) * 32 + ((q ^ swz) << 3);
  // staging: lane l writes stored col-block (l&3) of row base+(l>>2);
  // source logical block = (l&3) ^ ((row>>1)&3) = (l&3) ^ ((l>>3)&3)
  const int permc = (((l & 3) ^ ((l >> 3) & 3)) << 3);
  const ushort_t* ag0 = Ag + (size_t)(bm + (MR / 8) * w + (l >> 2)) * lda + permc;
  const ushort_t* ag1 = ag0 + (size_t)16 * lda;        // MR==256 only
  int br0 = bn + 32 * w + (l >> 2);      if (br0 > brmax) br0 = brmax;
  int br1 = bn + 32 * w + 16 + (l >> 2); if (br1 > brmax) br1 = brmax;
  const ushort_t* bg0 = Bg + (size_t)br0 * ldb + permc;
  const ushort_t* bg1 = Bg + (size_t)br1 * ldb + permc;
  ushort_t* alw = As + ((MR == 256) ? (2 * w * 512) : (w * 512));
  ushort_t* blw = Bs + 2 * w * 512;

#define STAGE_A_(kt_)                                                        \
  { const int k_ = (kt_) << 5;                                               \
    ushort_t* sa_ = alw + ((kt_) & 3) * ASLOT;                               \
    gl_lds16(ag0 + k_, sa_);                                                 \
    if (MR == 256) gl_lds16(ag1 + k_, sa_ + 512); }
#define STAGE_B_(kt_)                                                        \
  { const int k_ = (kt_) << 5;                                               \
    ushort_t* sb_ = blw + ((kt_) & 3) * BSLOT;                               \
    gl_lds16(bg0 + k_, sb_);                                                 \
    gl_lds16(bg1 + k_, sb_ + 512); }

  // prologue: stage tiles 0,1,2 (nkt >= 3 always here)
  STAGE_A_(0); STAGE_B_(0);
  STAGE_A_(1); STAGE_B_(1);
  STAGE_A_(2); STAGE_B_(2);

#pragma unroll
  for (int i = 0; i < MF; ++i)
#pragma unroll
    for (int j = 0; j < 4; ++j) acc[i][j] = (f32x4){0.f, 0.f, 0.f, 0.f};

#pragma unroll 1
  for (int kt = 0; kt < nkt; ++kt) {
    const ushort_t* Asl = As + (kt & 3) * ASLOT;
    const ushort_t* Bsl = Bs + (kt & 3) * BSLOT;
    // tiles kt+1,kt+2 may be in flight (2*LPT loads); all older must be done
    if (kt + 2 < nkt)      wait_vmcnt<2 * LPT>();
    else if (kt + 1 < nkt) wait_vmcnt<LPT>();
    else                   wait_vmcnt<0>();
    __builtin_amdgcn_s_barrier();
    asm volatile("" ::: "memory");
    const bool st = (kt + 3) < nkt;
    short8 bfr[4], af[MF / 2];
#pragma unroll
    for (int nf = 0; nf < 4; ++nf)
      bfr[nf] = *(const short8*)(Bsl + boff + nf * 512);
#pragma unroll
    for (int mf = 0; mf < MF / 2; ++mf)
      af[mf] = *(const short8*)(Asl + aoff + mf * 512);
    if (st) STAGE_A_(kt + 3);
    __builtin_amdgcn_s_setprio(1);
#pragma unroll
    for (int mf = 0; mf < MF / 2; ++mf)
#pragma unroll
      for (int nf = 0; nf < 4; ++nf)
        acc[mf][nf] = __builtin_amdgcn_mfma_f32_16x16x32_bf16(af[mf], bfr[nf], acc[mf][nf], 0, 0, 0);
    __builtin_amdgcn_s_setprio(0);
#pragma unroll
    for (int mf = 0; mf < MF / 2; ++mf)
      af[mf] = *(const short8*)(Asl + aoff + (mf + MF / 2) * 512);
    if (st) STAGE_B_(kt + 3);
    __builtin_amdgcn_s_setprio(1);
#pragma unroll
    for (int mf = 0; mf < MF / 2; ++mf)
#pragma unroll
      for (int nf = 0; nf < 4; ++nf)
        acc[mf + MF / 2][nf] = __builtin_amdgcn_mfma_f32_16x16x32_bf16(af[mf], bfr[nf], acc[mf + MF / 2][nf], 0, 0, 0);
    __builtin_amdgcn_s_setprio(0);
  }
#undef STAGE_A_
#undef STAGE_B_
}

// GEMM1 main: M=4096, N=10496 (z cols 0..10239, dt cols 10240..10303 fp32
// TRANSPOSED to dtraw[64][4096]; cols 10304..10495 garbage/discarded; B rows
// clamped). grid 656 = 16m x 41n.
__global__ __launch_bounds__(512, 2) void gemm1_256(const ushort_t* __restrict__ hsb,
                                                    const ushort_t* __restrict__ w_inb,
                                                    ushort_t* __restrict__ zb,
                                                    float* __restrict__ dtraw) {
  __shared__ __align__(16) ushort_t As[4 * 8192];
  __shared__ __align__(16) ushort_t Bs[4 * 8192];
  int bid = blockIdx.x;
  int wg = (bid & 7) * 82 + (bid >> 3);          // bijective XCD swizzle (656%8==0)
  int tm = wg & 15, tn = wg >> 4;                // tm in [0,16), tn in [0,41)
  int bm = tm * 256, bn = tn * 256;
  f32x4 acc[8][4];
  gemm_core<256>(hsb, w_inb, HID_, HID_, HID_ / 32, bm, bn, PROJ_ - 1, As, Bs, acc);
  int t = threadIdx.x, w = t >> 6, l = t & 63;
  int wm = w >> 2, wn = w & 3, ml = l & 15, quad = l >> 4;
  int rb = bm + wm * 128 + quad * 4;
  int cb = bn + wn * 64 + ml;
  if (tn < 40) {
#pragma unroll
    for (int mf = 0; mf < 8; ++mf)
#pragma unroll
      for (int r = 0; r < 4; ++r) {
        size_t row = (size_t)(rb + mf * 16 + r) * ZSTR_;
#pragma unroll
        for (int nf = 0; nf < 4; ++nf)
          zb[row + cb + nf * 16] = f2b(acc[mf][nf][r]);
      }
  } else if (wn == 0) {   // dt columns, transposed store: dtraw[h][token]
#pragma unroll
    for (int mf = 0; mf < 8; ++mf)
#pragma unroll
      for (int r = 0; r < 4; ++r) {
        int tok = rb + mf * 16 + r;
#pragma unroll
        for (int nf = 0; nf < 4; ++nf)
          dtraw[(size_t)(ml + nf * 16) * ML_ + tok] = acc[mf][nf][r];
      }
  }
}

// ---------------------------------------------------------------------------
// GEMM2: out = Y @ out_proj_w^T. M=4096, N=2048, K=4096.
// 128x128 tiles, 256 thr = 4 waves (2x2), 4x4 frags/wave. 3-slot LDS ring
// (48 KiB -> 2 resident blocks/CU: co-tenant hides barrier/vmcnt drains,
// unavailable to the previous grid-256 = 1-block/CU version).
// Same swizzle + single-barrier + counted-vmcnt discipline as gemm_core.
// Ring-3 safety: STAGE(kt+2) overwrites slot (kt-1)%3; every wave past tile
// kt's top barrier has issued its kt-1 MFMAs, so its ds_reads of kt-1 are
// register-complete.
// grid 512 = 32m x 16n, XCD-swizzled.
// ---------------------------------------------------------------------------
__global__ __launch_bounds__(256, 2) void gemm2_sq(const ushort_t* __restrict__ Ab,
                                                   const ushort_t* __restrict__ Bb,
                                                   float* __restrict__ C) {
  __shared__ __align__(16) ushort_t As[3 * 4096];
  __shared__ __align__(16) ushort_t Bs[3 * 4096];
  int bid = blockIdx.x;
  int wg = (bid & 7) * 64 + (bid >> 3);          // bijective (512%8==0)
  int tm = wg & 31, tn = wg >> 5;                // 32 x 16
  int bm = tm * 128, bn = tn * 128;
  const int t = threadIdx.x;
  const int w = t >> 6, l = t & 63;
  const int wm = w >> 1, wn = w & 1;
  const int ml = l & 15, q = l >> 4;
  const int swz = (ml >> 1) & 3;
  const int aoff = (wm * 64 + ml) * 32 + ((q ^ swz) << 3);
  const int boff = (wn * 64 + ml) * 32 + ((q ^ swz) << 3);
  // staging: thread t covers row 64u + (t>>2), stored blk (t&3);
  // source logical blk = (t&3) ^ ((row>>1)&3) = (t&3) ^ ((t>>3)&3)
  const int permc = (((t & 3) ^ ((t >> 3) & 3)) << 3);
  const ushort_t* ag0 = Ab + (size_t)(bm + (t >> 2)) * CONVD_ + permc;
  const ushort_t* ag1 = Ab + (size_t)(bm + 64 + (t >> 2)) * CONVD_ + permc;
  const ushort_t* bg0 = Bb + (size_t)(bn + (t >> 2)) * INTER_ + permc;
  const ushort_t* bg1 = Bb + (size_t)(bn + 64 + (t >> 2)) * INTER_ + permc;
  // gl_lds dest: wave-uniform base (slot + (64u + 16w)*32), lane*16 linear.
#define STG2_(kt_)                                                           \
  { const int sl_ = (kt_) % 3; const int k_ = (kt_) << 5;                    \
    gl_lds16(ag0 + k_, As + sl_ * 4096 + (16 * w) * 32);                     \
    gl_lds16(ag1 + k_, As + sl_ * 4096 + (64 + 16 * w) * 32);                \
    gl_lds16(bg0 + k_, Bs + sl_ * 4096 + (16 * w) * 32);                     \
    gl_lds16(bg1 + k_, Bs + sl_ * 4096 + (64 + 16 * w) * 32); }

  f32x4 acc[4][4];
#pragma unroll
  for (int i = 0; i < 4; ++i)
#pragma unroll
    for (int j = 0; j < 4; ++j) acc[i][j] = (f32x4){0.f, 0.f, 0.f, 0.f};

  STG2_(0);
  STG2_(1);
  constexpr int NKT = INTER_ / 32;      // 128
#pragma unroll 1
  for (int kt = 0; kt < NKT; ++kt) {
    const ushort_t* Asl = As + (kt % 3) * 4096;
    const ushort_t* Bsl = Bs + (kt % 3) * 4096;
    if (kt + 1 < NKT) wait_vmcnt<4>();   // kt+1's 4 loads may stay in flight
    else              wait_vmcnt<0>();
    __builtin_amdgcn_s_barrier();
    asm volatile("" ::: "memory");
    short8 af[4], bf[4];
#pragma unroll
    for (int mf = 0; mf < 4; ++mf)
      af[mf] = *(const short8*)(Asl + aoff + mf * 512);
#pragma unroll
    for (int nf = 0; nf < 4; ++nf)
      bf[nf] = *(const short8*)(Bsl + boff + nf * 512);
    if (kt + 2 < NKT) STG2_(kt + 2);
    __builtin_amdgcn_s_setprio(1);
#pragma unroll
    for (int mf = 0; mf < 4; ++mf)
#pragma unroll
      for (int nf = 0; nf < 4; ++nf)
        acc[mf][nf] = __builtin_amdgcn_mfma_f32_16x16x32_bf16(af[mf], bf[nf], acc[mf][nf], 0, 0, 0);
    __builtin_amdgcn_s_setprio(0);
  }
#undef STG2_
  int rb = bm + wm * 64 + q * 4;
  int cbc = bn + wn * 64 + ml;
#pragma unroll
  for (int mf = 0; mf < 4; ++mf)
#pragma unroll
    for (int r = 0; r < 4; ++r) {
      size_t row = (size_t)(rb + mf * 16 + r) * HID_;
#pragma unroll
      for (int nf = 0; nf < 4; ++nf)
        C[row + cbc + nf * 16] = acc[mf][nf][r];
    }
}

// ---------------------------------------------------------------------------
// Fused launch: blocks [0,1536) causal depthwise conv (K=4)+SiLU;
// blocks [1536,2560) dt softplus+cumsum (shuffle scan, 1 barrier).
// ---------------------------------------------------------------------------
#define CROWS_ 8
__global__ __launch_bounds__(256) void conv_dt_k(const ushort_t* __restrict__ zb,
                                                 const float* __restrict__ cw,
                                                 const float* __restrict__ cb,
                                                 ushort_t* __restrict__ xcb,
                                                 const float* __restrict__ dtraw,
                                                 const float* __restrict__ dt_bias,
                                                 const float* __restrict__ A_log,
                                                 float* __restrict__ dtp,
                                                 float* __restrict__ dacs,
                                                 float* __restrict__ cdec) {
  __shared__ float sm[4];
  int bid = blockIdx.x;
  if (bid < 1536) {
    // ---- conv + SiLU ----
    int grp = bid & 511;                 // ML_/CROWS_ = 512 row groups
    int seg = bid >> 9;                  // 3 segs x 2048 channels
    int u = threadIdx.x;                 // unit (8 channels) within seg
    int c8 = seg * 2048 + u * 8;
    int row0 = grp * CROWS_;             // groups never cross batch
    int l0 = row0 & (L_ - 1);

    float wv[K_][8], bias[8];
    {
      const float4* wp = (const float4*)(cw + (size_t)c8 * K_);
#pragma unroll
      for (int c = 0; c < 8; ++c) {
        float4 w4 = wp[c];
        wv[0][c] = w4.x; wv[1][c] = w4.y; wv[2][c] = w4.z; wv[3][c] = w4.w;
      }
      float4 b0 = *(const float4*)(cb + c8);
      float4 b1 = *(const float4*)(cb + c8 + 4);
      bias[0] = b0.x; bias[1] = b0.y; bias[2] = b0.z; bias[3] = b0.w;
      bias[4] = b1.x; bias[5] = b1.y; bias[6] = b1.z; bias[7] = b1.w;
    }
    const ushort_t* xin = zb + (size_t)row0 * ZSTR_ + INTER_ + c8;
    ushort_t* xout = xcb + (size_t)row0 * CONVD_ + c8;

    float win[4][8];
#pragma unroll
    for (int i = 0; i < 3; ++i) {
      if (l0 > 0) {
        ld_bf8(xin + (ptrdiff_t)(i - 3) * ZSTR_, win[i]);
      } else {
#pragma unroll
        for (int c = 0; c < 8; ++c) win[i][c] = 0.f;   // zero-pad (matches ref)
      }
    }
#pragma unroll
    for (int r = 0; r < CROWS_; ++r) {
      ld_bf8(xin + (size_t)r * ZSTR_, win[(r + 3) & 3]);
      float a[8];
#pragma unroll
      for (int c = 0; c < 8; ++c) {
        float v = bias[c];
        v = fmaf(wv[0][c], win[(r + 0) & 3][c], v);
        v = fmaf(wv[1][c], win[(r + 1) & 3][c], v);
        v = fmaf(wv[2][c], win[(r + 2) & 3][c], v);
        v = fmaf(wv[3][c], win[(r + 3) & 3][c], v);
        a[c] = v / (1.f + __expf(-v));
      }
      st_bf8(xout + (size_t)r * CONVD_, a);
    }
  } else {
    // ---- dt: softplus + per-chunk cumsum (wave shuffle scan) ----
    int bzh = bid - 1536;
    int h = bzh & 63, z = (bzh >> 6) & 7, b = bzh >> 9;
    int i = threadIdx.x;
    size_t row = (size_t)b * L_ + z * CS_ + i;
    float dv = dtraw[(size_t)h * ML_ + row] + dt_bias[h];
    float sp = (dv > 20.f) ? dv : log1pf(expf(dv));
    float s = sp * (-expf(A_log[h]));
    int lane = i & 63;
#pragma unroll
    for (int off = 1; off < 64; off <<= 1) {
      float uo = __shfl_up(s, off);
      if (lane >= off) s += uo;
    }
    if (lane == 63) sm[i >> 6] = s;
    __syncthreads();
    float pre = 0.f;
#pragma unroll
    for (int w2 = 0; w2 < 3; ++w2)
      if (w2 < (i >> 6)) pre += sm[w2];
    float cs = s + pre;
    size_t ob = ((size_t)b * H_ + h) * L_ + z * CS_ + i;
    dtp[ob] = sp;
    dacs[ob] = cs;
    if (i == CS_ - 1) cdec[bzh] = expf(cs);
  }
}

// ---------------------------------------------------------------------------
// CB[i,j] = sum_n C[i,n]*B[j,n], lower-triangular 64x64 tiles. bf16 out.
// MFMA version with 16-block XOR swizzle. grid (10, 128).
// ---------------------------------------------------------------------------
__global__ __launch_bounds__(256) void cb_k(const ushort_t* __restrict__ xcb,
                                            ushort_t* __restrict__ CBo) {
  static const unsigned char itab[10] = {0, 1, 1, 2, 2, 2, 3, 3, 3, 3};
  static const unsigned char jtab[10] = {0, 0, 1, 0, 1, 2, 0, 1, 2, 3};
  int tp = blockIdx.x;
  int it = itab[tp], jt = jtab[tp];
  int bzg = blockIdx.y;
  int g = bzg & 7, z = (bzg >> 3) & 7, b = bzg >> 6;
  int t = threadIdx.x;
  int w = t >> 6, l = t & 63;
  __shared__ __align__(16) ushort_t Cs[64 * 128];
  __shared__ __align__(16) ushort_t Bs[64 * 128];
  size_t rowbase = (size_t)b * L_ + (size_t)z * CS_;
  {   // stage: wave w covers rows 16w..16w+15, 4 rows per gl_lds issue
    int s = l & 15;                        // stored 16B block within row
    int cO = INTER_ + G_ * N_ + g * N_;
    int bO = INTER_ + g * N_;
#pragma unroll
    for (int i = 0; i < 4; ++i) {
      int row = 16 * w + 4 * i + (l >> 4); // local row this lane writes
      int src = ((s ^ (row & 15)) << 3);   // pre-swizzled source col (elems)
      gl_lds16(xcb + (rowbase + it * 64 + row) * CONVD_ + cO + src,
               Cs + (16 * w + 4 * i) * 128);
      gl_lds16(xcb + (rowbase + jt * 64 + row) * CONVD_ + bO + src,
               Bs + (16 * w + 4 * i) * 128);
    }
  }
  asm volatile("s_waitcnt vmcnt(0)" ::: "memory");
  __builtin_amdgcn_s_barrier();
  // wave w -> 32x32 output tile (wm = w>>1, wn = w&1)
  int wm = w >> 1, wn = w & 1;
  int ml = l & 15, q = l >> 4;
  f32x4 acc[2][2];
#pragma unroll
  for (int i = 0; i < 2; ++i)
#pragma unroll
    for (int j = 0; j < 2; ++j) acc[i][j] = (f32x4){0.f, 0.f, 0.f, 0.f};
#pragma unroll
  for (int kk = 0; kk < 4; ++kk) {
    short8 af[2], bf[2];
#pragma unroll
    for (int mf = 0; mf < 2; ++mf) {
      int row = wm * 32 + mf * 16 + ml;
      af[mf] = *(const short8*)(Cs + row * 128 + (((kk * 4 + q) ^ (row & 15)) << 3));
    }
#pragma unroll
    for (int nf = 0; nf < 2; ++nf) {
      int row = wn * 32 + nf * 16 + ml;
      bf[nf] = *(const short8*)(Bs + row * 128 + (((kk * 4 + q) ^ (row & 15)) << 3));
    }
#pragma unroll
    for (int mf = 0; mf < 2; ++mf)
#pragma unroll
      for (int nf = 0; nf < 2; ++nf)
        acc[mf][nf] = __builtin_amdgcn_mfma_f32_16x16x32_bf16(af[mf], bf[nf], acc[mf][nf], 0, 0, 0);
  }
  // epilogue: D col = lane&15 (j), row = (lane>>4)*4 + reg (i)
  size_t cbase = ((size_t)((b * 8 + z) * 8 + g)) * (CS_ * CS_);
#pragma unroll
  for (int mf = 0; mf < 2; ++mf)
#pragma unroll
    for (int nf = 0; nf < 2; ++nf)
#pragma unroll
      for (int r = 0; r < 4; ++r) {
        int i = wm * 32 + mf * 16 + q * 4 + r;
        int j = wn * 32 + nf * 16 + ml;
        CBo[cbase + (size_t)(it * 64 + i) * CS_ + jt * 64 + j] = f2b(acc[mf][nf][r]);
      }
}

// ---------------------------------------------------------------------------
// states (MFMA): S[p,n] = sum_j x[j,p]*w[j]*B[j,n] per (b,z,h).
// Staging writes PAIRED (2 j's per thread -> b32 LDS writes).
// ---------------------------------------------------------------------------
__global__ __launch_bounds__(256) void states_mfma(const ushort_t* __restrict__ xcb,
                                                   const float* __restrict__ dacs,
                                                   const float* __restrict__ dtp,
                                                   float* __restrict__ st) {
  int bzh = blockIdx.x;
  int h = bzh & 63, z = (bzh >> 6) & 7, b = bzh >> 9;
  int g = h >> 3;
  int t = threadIdx.x;
  int wv = t >> 6, lane = t & 63;
  int ml = lane & 15, ko = (lane >> 4) * 8;
  __shared__ float ws[256];
  __shared__ __align__(16) ushort_t Xw[64 * 136];    // (w*x)^T [p][j_half]
  __shared__ __align__(16) ushort_t Bt[128 * 136];   // B^T [n][j_half]
  size_t base = ((size_t)b * H_ + h) * L_ + z * CS_;
  float dlast = dacs[base + CS_ - 1];
  ws[t] = __expf(dlast - dacs[base + t]) * dtp[base + t];
  size_t rowbase = (size_t)b * L_ + z * CS_;
  f32x4 acc[4][2];
#pragma unroll
  for (int i = 0; i < 4; ++i) {
    acc[i][0] = (f32x4){0.f, 0.f, 0.f, 0.f};
    acc[i][1] = (f32x4){0.f, 0.f, 0.f, 0.f};
  }
  for (int half = 0; half < 2; ++half) {
    int j0 = half * 128;
    __syncthreads();
    {   // stage Xw: x[j][p]*w[j] -> Xw[p][j], 2 j x 16 p per thread
      int j2 = (t & 63) * 2, pseg = (t >> 6) * 16;
      const ushort_t* xr0 = xcb + (rowbase + j0 + j2) * CONVD_ + h * P_ + pseg;
      const ushort_t* xr1 = xr0 + CONVD_;
      float w0 = ws[j0 + j2], w1 = ws[j0 + j2 + 1];
      float v0[8], v0b[8], v1[8], v1b[8];
      ld_bf8(xr0, v0); ld_bf8(xr0 + 8, v0b);
      ld_bf8(xr1, v1); ld_bf8(xr1 + 8, v1b);
      unsigned* xw32 = (unsigned*)Xw;
      int col = t & 63;                  // u32 column = j2/2
#pragma unroll
      for (int pp = 0; pp < 8; ++pp) {
        unsigned lo = f2b(v0[pp] * w0), hi = f2b(v1[pp] * w1);
        xw32[(pseg + pp) * 68 + col] = lo | (hi << 16);
      }
#pragma unroll
      for (int pp = 0; pp < 8; ++pp) {
        unsigned lo = f2b(v0b[pp] * w0), hi = f2b(v1b[pp] * w1);
        xw32[(pseg + 8 + pp) * 68 + col] = lo | (hi << 16);
      }
    }
    {   // stage Bt: B[j][n] -> Bt[n][j], 2 j x 32 n per thread
      int j2 = (t & 63) * 2, nseg = (t >> 6) * 32;
      const ushort_t* br0 = xcb + (rowbase + j0 + j2) * CONVD_ + INTER_ + g * N_ + nseg;
      const ushort_t* br1 = br0 + CONVD_;
      unsigned* bt32 = (unsigned*)Bt;
      int col = t & 63;
#pragma unroll
      for (int qq = 0; qq < 4; ++qq) {
        uint4 r0 = *(const uint4*)(br0 + qq * 8);
        uint4 r1 = *(const uint4*)(br1 + qq * 8);
        const ushort_t* s0 = (const ushort_t*)&r0;
        const ushort_t* s1 = (const ushort_t*)&r1;
#pragma unroll
        for (int c = 0; c < 8; ++c)
          bt32[(nseg + qq * 8 + c) * 68 + col] = (unsigned)s0[c] | ((unsigned)s1[c] << 16);
      }
    }
    __syncthreads();
#pragma unroll
    for (int k0 = 0; k0 < 128; k0 += 32) {
      short8 af[4], bf2[2];
#pragma unroll
      for (int mf = 0; mf < 4; ++mf)
        af[mf] = *(const short8*)(Xw + (mf * 16 + ml) * 136 + k0 + ko);
#pragma unroll
      for (int nf = 0; nf < 2; ++nf)
        bf2[nf] = *(const short8*)(Bt + (wv * 32 + nf * 16 + ml) * 136 + k0 + ko);
#pragma unroll
      for (int mf = 0; mf < 4; ++mf)
#pragma unroll
        for (int nf = 0; nf < 2; ++nf)
          acc[mf][nf] = __builtin_amdgcn_mfma_f32_16x16x32_bf16(af[mf], bf2[nf], acc[mf][nf], 0, 0, 0);
    }
  }
  float* outp = st + ((size_t)((b * 8 + z) * H_ + h)) * (P_ * N_);
  int quad = lane >> 4;
#pragma unroll
  for (int mf = 0; mf < 4; ++mf)
#pragma unroll
    for (int nf = 0; nf < 2; ++nf) {
      int n = wv * 32 + nf * 16 + ml;
#pragma unroll
      for (int r = 0; r < 4; ++r) {
        int p = mf * 16 + quad * 4 + r;
        outp[(size_t)p * N_ + n] = acc[mf][nf][r];
      }
    }
}

// ---------------------------------------------------------------------------
// Inter-chunk exclusive scan over nc=8 chunks, IN PLACE on st.
// ---------------------------------------------------------------------------
__global__ __launch_bounds__(256) void scan_k(float* __restrict__ st,
                                              const float* __restrict__ cdec) {
  size_t idx = (size_t)blockIdx.x * 256 + threadIdx.x;
  int b = (int)(idx >> 19);            // 524288 = H_*P_*N_
  size_t rem = idx & 524287;
  int h = (int)(rem >> 13);            // 8192 = P_*N_
  float S = 0.f;
#pragma unroll
  for (int z = 0; z < NC_; ++z) {
    size_t off = (size_t)(b * 8 + z) * 524288 + rem;
    float old = st[off];
    st[off] = S;
    S = cdec[(b * 8 + z) * H_ + h] * S + old;
  }
}

// ---------------------------------------------------------------------------
// y (MFMA): Y^T[p][i] = exp(dA_i)*(prev@C^T) + M@x^T, + D*x, per (b,z,h).
// Phase B: CB rows register-prefetched one iteration ahead.
// ---------------------------------------------------------------------------
__global__ __launch_bounds__(256) void y_mfma(const ushort_t* xcb,
                                              const ushort_t* __restrict__ CB,
                                              const float* __restrict__ pv,
                                              const float* __restrict__ dacs,
                                              const float* __restrict__ dtp,
                                              const float* __restrict__ Dw,
                                              ushort_t* Yx) {
  int bzh = blockIdx.x;
  int h = bzh & 63, z = (bzh >> 6) & 7, b = bzh >> 9;
  int g = h >> 3;
  int t = threadIdx.x;
  int wv = t >> 6, lane = t & 63;
  int ml = lane & 15, quad = lane >> 4, ko = quad * 8;
  __shared__ __align__(16) ushort_t Ms[256 * 40];    // Phase B M; Phase A Cs[256*32]
  __shared__ __align__(16) ushort_t XsYs[18432];     // Xs [64][264]; epilogue Ys [256][72]
  __shared__ __align__(16) ushort_t Ps[64 * 136];    // prev bf16 [p][n]
  __shared__ float dAs[256], dts[256];

  size_t rowbase = (size_t)b * L_ + z * CS_;
  {
    size_t base = ((size_t)b * H_ + h) * L_ + z * CS_;
    dAs[t] = dacs[base + t];
    dts[t] = dtp[base + t];
  }
  {   // stage prev fp32 -> bf16 Ps[p][n] (pad 136)
    int p = t >> 2, c0 = (t & 3) * 32;
    const float* pr = pv + ((size_t)((b * 8 + z) * H_ + h)) * (P_ * N_) + (size_t)p * N_ + c0;
    ushort_t* dst = Ps + p * 136 + c0;
#pragma unroll
    for (int u = 0; u < 4; ++u) {
      float4 a = *(const float4*)(pr + u * 8);
      float4 bq = *(const float4*)(pr + u * 8 + 4);
      float v[8] = {a.x, a.y, a.z, a.w, bq.x, bq.y, bq.z, bq.w};
      st_bf8(dst + u * 8, v);
    }
  }
  {   // stage Xs = x^T: read x[i=t][0..63], scatter to Xs[p][t]
    const ushort_t* xr = xcb + (rowbase + t) * CONVD_ + h * P_;
    ushort_t* Xs = XsYs;
#pragma unroll
    for (int q = 0; q < 8; ++q) {
      uint4 raw = *(const uint4*)(xr + q * 8);
      const ushort_t* s = (const ushort_t*)&raw;
#pragma unroll
      for (int c = 0; c < 8; ++c) Xs[(q * 8 + c) * 264 + t] = s[c];
    }
  }

  f32x4 acc[4][4];
#pragma unroll
  for (int i = 0; i < 4; ++i)
#pragma unroll
    for (int j = 0; j < 4; ++j) acc[i][j] = (f32x4){0.f, 0.f, 0.f, 0.f};

  // ---- Phase A: Y_off^T[p][i] = sum_n prev[p][n] * C[i][n]
  int cOff = INTER_ + G_ * N_ + g * N_;
#pragma unroll
  for (int k0 = 0; k0 < 128; k0 += 32) {
    __syncthreads();
#pragma unroll
    for (int u = 0; u < 4; ++u) {   // stage Cs tile [256][32] via global_load_lds
      int sid = u * 256 + t;
      int row = sid >> 2, kc = (sid & 3) * 8;
      gl_lds16(xcb + (rowbase + row) * CONVD_ + cOff + k0 + kc,
               Ms + (size_t)(u * 256 + wv * 64) * 8);
    }
    __syncthreads();
    short8 af[4], bf[4];
#pragma unroll
    for (int mf = 0; mf < 4; ++mf)
      af[mf] = *(const short8*)(Ps + (mf * 16 + ml) * 136 + k0 + ko);
#pragma unroll
    for (int nf = 0; nf < 4; ++nf)
      bf[nf] = *(const short8*)(Ms + (wv * 64 + nf * 16 + ml) * 32 + ko);
#pragma unroll
    for (int mf = 0; mf < 4; ++mf)
#pragma unroll
      for (int nf = 0; nf < 4; ++nf)
        acc[mf][nf] = __builtin_amdgcn_mfma_f32_16x16x32_bf16(af[mf], bf[nf], acc[mf][nf], 0, 0, 0);
  }
  // scale by exp(dA_i), i = column index
#pragma unroll
  for (int nf = 0; nf < 4; ++nf) {
    float e = __expf(dAs[wv * 64 + nf * 16 + ml]);
#pragma unroll
    for (int mf = 0; mf < 4; ++mf) {
      acc[mf][nf][0] *= e; acc[mf][nf][1] *= e;
      acc[mf][nf][2] *= e; acc[mf][nf][3] *= e;
    }
  }

  // ---- Phase B: Y_diag^T[p][i] = sum_j M[i][j] * x[j][p]
  float dAi_t = dAs[t];
  size_t cbase = ((size_t)((b * 8 + z) * 8 + g)) * (CS_ * CS_) + (size_t)t * CS_;
  const ushort_t* Xs = XsYs;
  uint4 pre[4];
  {
    const ushort_t* cbr = CB + cbase;
#pragma unroll
    for (int qq = 0; qq < 4; ++qq) pre[qq] = *(const uint4*)(cbr + qq * 8);
  }
  for (int j0 = 0; j0 < 256; j0 += 32) {
    __syncthreads();
    {   // build M row i=t, cols j0..j0+31 into Ms[t][0..31] (stride 40)
      ushort_t* mrow = Ms + t * 40;
#pragma unroll
      for (int qq = 0; qq < 4; ++qq) {
        const ushort_t* s = (const ushort_t*)&pre[qq];
        float o[8];
#pragma unroll
        for (int c = 0; c < 8; ++c) {
          int j = j0 + qq * 8 + c;
          float m = b2f(s[c]) * __expf(dAi_t - dAs[j]) * dts[j];
          o[c] = (j <= t) ? m : 0.f;
        }
        st_bf8(mrow + qq * 8, o);
      }
    }
    uint4 nxt[4];
    if (j0 + 32 < 256) {   // issue next iteration's CB loads (hide under MFMA)
      const ushort_t* cbr = CB + cbase + j0 + 32;
#pragma unroll
      for (int qq = 0; qq < 4; ++qq) nxt[qq] = *(const uint4*)(cbr + qq * 8);
    }
    __syncthreads();
    short8 af[4], bf[4];
#pragma unroll
    for (int mf = 0; mf < 4; ++mf)
      af[mf] = *(const short8*)(Xs + (mf * 16 + ml) * 264 + j0 + ko);
#pragma unroll
    for (int nf = 0; nf < 4; ++nf)
      bf[nf] = *(const short8*)(Ms + (wv * 64 + nf * 16 + ml) * 40 + ko);
#pragma unroll
    for (int mf = 0; mf < 4; ++mf)
#pragma unroll
      for (int nf = 0; nf < 4; ++nf)
        acc[mf][nf] = __builtin_amdgcn_mfma_f32_16x16x32_bf16(af[mf], bf[nf], acc[mf][nf], 0, 0, 0);
#pragma unroll
    for (int qq = 0; qq < 4; ++qq) pre[qq] = nxt[qq];
  }

  // ---- Epilogue: transpose acc through LDS (Ys over Xs), +D*x, store
  __syncthreads();
  ushort_t* Ys = XsYs;   // [256][72]
#pragma unroll
  for (int mf = 0; mf < 4; ++mf)
#pragma unroll
    for (int nf = 0; nf < 4; ++nf) {
      int iw = wv * 64 + nf * 16 + ml;
      int pb = mf * 16 + quad * 4;
      uint2 pk;
      ushort_t* s = (ushort_t*)&pk;
      s[0] = f2b(acc[mf][nf][0]); s[1] = f2b(acc[mf][nf][1]);
      s[2] = f2b(acc[mf][nf][2]); s[3] = f2b(acc[mf][nf][3]);
      *(uint2*)(Ys + iw * 72 + pb) = pk;
    }
  __syncthreads();
  {
    float Dh = Dw[h];
    const ushort_t* xr = xcb + (rowbase + t) * CONVD_ + h * P_;
    ushort_t* yr = Yx + (rowbase + t) * CONVD_ + h * P_;
#pragma unroll
    for (int q = 0; q < 8; ++q) {
      float xv[8], yv[8], o[8];
      ld_bf8(xr + q * 8, xv);
      ld_bf8(Ys + t * 72 + q * 8, yv);
#pragma unroll
      for (int c = 0; c < 8; ++c) o[c] = yv[c] + Dh * xv[c];
      st_bf8(yr + q * 8, o);
    }
  }
}

// ---------------------------------------------------------------------------
// Fused launch: blocks [0,4096) RMSNorm + silu(z) gate (in-place on xcb
// x-slice); blocks [4096,8192) cast w_out fp32 -> bf16 (independent work).
// ---------------------------------------------------------------------------
__global__ __launch_bounds__(256) void rms_cast2_k(ushort_t* __restrict__ Y,
                                                   const ushort_t* __restrict__ zb,
                                                   const float* __restrict__ nw,
                                                   const float* __restrict__ w_out,
                                                   ushort_t* __restrict__ w_outb) {
  __shared__ float red[4];
  int bid = blockIdx.x;
  int t = threadIdx.x;
  if (bid >= ML_) {
    size_t e8 = ((size_t)(bid - ML_) * 256 + t) * 8;
    float4 a = *(const float4*)(w_out + e8);
    float4 b = *(const float4*)(w_out + e8 + 4);
    float v[8] = {a.x, a.y, a.z, a.w, b.x, b.y, b.z, b.w};
    st_bf8(w_outb + e8, v);
    return;
  }
  int row = bid;
  ushort_t* y = Y + (size_t)row * CONVD_;
  const ushort_t* zp = zb + (size_t)row * ZSTR_;
  float v[2][8];
  float s = 0.f;
#pragma unroll
  for (int u = 0; u < 2; ++u) {
    ld_bf8(y + u * 2048 + t * 8, v[u]);
#pragma unroll
    for (int c = 0; c < 8; ++c) s += v[u][c] * v[u][c];
  }
#pragma unroll
  for (int off = 32; off > 0; off >>= 1) s += __shfl_down(s, off);
  if ((t & 63) == 0) red[t >> 6] = s;
  __syncthreads();
  float tot = red[0] + red[1] + red[2] + red[3];
  float rstd = rsqrtf(tot * (1.f / INTER_) + EPS_);
#pragma unroll
  for (int u = 0; u < 2; ++u) {
    int c0 = u * 2048 + t * 8;
    float zv[8], o[8];
    ld_bf8(zp + c0, zv);
    float4 w0 = *(const float4*)(nw + c0);
    float4 w1 = *(const float4*)(nw + c0 + 4);
    float wv[8] = {w0.x, w0.y, w0.z, w0.w, w1.x, w1.y, w1.z, w1.w};
#pragma unroll
    for (int c = 0; c < 8; ++c)
      o[c] = wv[c] * v[u][c] * rstd * (zv[c] / (1.f + __expf(-zv[c])));
    st_bf8(y + c0, o);
  }
}

// ---------------------------------------------------------------------------
extern "C" void kernel_launch(void* const* d_in, const int* in_sizes, int n_in,
                              void* d_out, int out_size, void* d_ws, size_t ws_size,
                              hipStream_t stream) {
  const float* hs    = (const float*)d_in[0];
  const float* w_in  = (const float*)d_in[1];
  const float* cw    = (const float*)d_in[2];
  const float* cb    = (const float*)d_in[3];
  const float* dtb   = (const float*)d_in[4];
  const float* alog  = (const float*)d_in[5];
  const float* Dw    = (const float*)d_in[6];
  const float* nw    = (const float*)d_in[7];
  const float* w_out = (const float*)d_in[8];
  float* out = (float*)d_out;

  // Workspace layout (~187.3 MiB), regions R1/R2 time-aliased:
  //   R1: hsb [cast1,gemm1] -> cbuf [cb_k..y] -> w_outb [rms_cast2,gemm2]
  //   R2: w_inb [cast1,gemm1] -> st [states..y]
  char* base = (char*)d_ws;
  ushort_t* zb    = (ushort_t*)(base);                         //  83,886,080 B
  ushort_t* xcb   = (ushort_t*)(base + 83886080);              //  50,331,648 B
  float*    dtraw = (float*)(base + 134217728);                //   1,048,576 B
  float*    dtp   = (float*)(base + 135266304);                //   1,048,576 B
  float*    dacs  = (float*)(base + 136314880);                //   1,048,576 B
  float*    cdec  = (float*)(base + 137363456);                //       4,096 B
  char*     R1    = base + 137367552;                          //  16,777,216 B
  char*     R2    = base + 154144768;                          //  42,205,184 B
  ushort_t* hsb    = (ushort_t*)R1;
  ushort_t* cbuf   = (ushort_t*)R1;
  ushort_t* w_outb = (ushort_t*)R1;
  ushort_t* w_inb  = (ushort_t*)R2;
  float*    st     = (float*)R2;

  cast1_k<<<14400, 256, 0, stream>>>(hs, w_in, hsb, w_inb);
  gemm1_256<<<656, 512, 0, stream>>>(hsb, w_inb, zb, dtraw);
  conv_dt_k<<<2560, 256, 0, stream>>>(zb, cw, cb, xcb, dtraw, dtb, alog, dtp, dacs, cdec);
  cb_k<<<dim3(10, B_ * NC_ * G_), 256, 0, stream>>>(xcb, cbuf);
  states_mfma<<<B_ * NC_ * H_, 256, 0, stream>>>(xcb, dacs, dtp, st);
  scan_k<<<(B_ * H_ * P_ * N_) / 256, 256, 0, stream>>>(st, cdec);
  y_mfma<<<B_ * NC_ * H_, 256, 0, stream>>>(xcb, cbuf, st, dacs, dtp, Dw, xcb);
  rms_cast2_k<<<8192, 256, 0, stream>>>(xcb, zb, nw, w_out, w_outb);
  gemm2_sq<<<512, 256, 0, stream>>>(xcb, w_outb, out);
}